// Round 8
// baseline (352.888 us; speedup 1.0000x reference)
//
#include <hip/hip_runtime.h>

// ---------------- problem constants ----------------
#define NBATCH 4
#define SEQ    4096
#define DMODEL 512
#define NHEAD  8
#define HDIM   64
#define NSN    32
#define NXT    2048
#define QLEN   2080   // NXT + NSN
#define KLEN   4128   // SEQ + NSN

using bf16x8 = __attribute__((ext_vector_type(8))) short;
using f32x4  = __attribute__((ext_vector_type(4))) float;

typedef __attribute__((address_space(1))) unsigned int gu32;
typedef __attribute__((address_space(3))) unsigned int lu32;

// Q projection pre-scale: SCALE * log2(e) — softmax runs in exp2 domain
#define QSCALE 0.18033688f

__device__ __forceinline__ unsigned short f2bf(float f) {
  unsigned int u = __float_as_uint(f);
  u += 0x7FFF + ((u >> 16) & 1);          // RTNE
  return (unsigned short)(u >> 16);
}

__device__ __forceinline__ f32x4 mfma16(bf16x8 a, bf16x8 b, f32x4 c) {
  return __builtin_amdgcn_mfma_f32_16x16x32_bf16(a, b, c, 0, 0, 0);
}

__device__ __forceinline__ void gload_lds16(const void* g, void* lds_base) {
  __builtin_amdgcn_global_load_lds((const gu32*)g, (lu32*)lds_base, 16, 0, 0);
}

// DPP 16-lane reductions (VALU only)
template <int C>
__device__ __forceinline__ float fmax_dpp(float v) {
  int o = __builtin_amdgcn_update_dpp(0, __float_as_int(v), C, 0xF, 0xF, false);
  return fmaxf(v, __int_as_float(o));
}
__device__ __forceinline__ float red_max16(float v) {
  v = fmax_dpp<0xB1>(v);   // quad_perm xor1
  v = fmax_dpp<0x4E>(v);   // quad_perm xor2
  v = fmax_dpp<0x141>(v);  // row_half_mirror
  v = fmax_dpp<0x140>(v);  // row_mirror
  return v;
}

// ---------------- fp32 -> bf16 converts ----------------
__global__ __launch_bounds__(256) void cvt_f32_bf16_v4(const float* __restrict__ src,
                                                       unsigned short* __restrict__ dst, int n4) {
  int i = blockIdx.x * 256 + threadIdx.x;
  if (i >= n4) return;
  float4 v = reinterpret_cast<const float4*>(src)[i];
  ushort4 r;
  r.x = f2bf(v.x); r.y = f2bf(v.y); r.z = f2bf(v.z); r.w = f2bf(v.w);
  reinterpret_cast<ushort4*>(dst)[i] = r;
}

__global__ __launch_bounds__(256) void cvt_w4(const float* __restrict__ a, const float* __restrict__ b,
                                              const float* __restrict__ c, const float* __restrict__ d,
                                              unsigned short* __restrict__ dst) {
  const float* s = blockIdx.y == 0 ? a : blockIdx.y == 1 ? b : blockIdx.y == 2 ? c : d;
  int i = blockIdx.x * 256 + threadIdx.x;   // 65536 float4 per matrix
  float4 v = reinterpret_cast<const float4*>(s)[i];
  ushort4 r;
  r.x = f2bf(v.x); r.y = f2bf(v.y); r.z = f2bf(v.z); r.w = f2bf(v.w);
  reinterpret_cast<ushort4*>(dst)[(size_t)blockIdx.y * 65536 + i] = r;
}

// ---------------- seq projection GEMM (m97 structure, known-good) ----------------
__global__ __launch_bounds__(256) void proj_gemm(const unsigned short* __restrict__ X,
                                                 const unsigned short* __restrict__ W,
                                                 unsigned short* __restrict__ Out,
                                                 int rpb_shift, int row_off, int out_L, float scale) {
  __shared__ unsigned short As[128 * 32];
  __shared__ unsigned short Bs[128 * 32];
  const int tid = threadIdx.x;
  const int w = tid >> 6, l = tid & 63;
  const int lg = l >> 4, lr = l & 15;
  const int row0 = blockIdx.x * 128, col0 = blockIdx.y * 128;
  const int wr = (w >> 1) * 64, wc = (w & 1) * 64;
  const int mask = (1 << rpb_shift) - 1;

  f32x4 acc[4][4];
#pragma unroll
  for (int m = 0; m < 4; ++m)
#pragma unroll
    for (int n = 0; n < 4; ++n) acc[m][n] = (f32x4){0.f, 0.f, 0.f, 0.f};

  const int sr = w * 16 + (l >> 2);
  const int sc = (l & 3) * 8;

  for (int k0 = 0; k0 < 512; k0 += 32) {
#pragma unroll
    for (int i = 0; i < 2; ++i) {
      int gr = row0 + sr + i * 64;
      int xrow = ((gr >> rpb_shift) << 12) + row_off + (gr & mask);
      const unsigned short* gpa = X + (size_t)xrow * 512 + k0 + sc;
      gload_lds16(gpa, (char*)As + i * 4096 + w * 1024);
      const unsigned short* gpb = W + (size_t)(col0 + sr + i * 64) * 512 + k0 + sc;
      gload_lds16(gpb, (char*)Bs + i * 4096 + w * 1024);
    }
    __syncthreads();
    bf16x8 av[4], bv[4];
#pragma unroll
    for (int m = 0; m < 4; ++m) av[m] = *(const bf16x8*)&As[(wr + m * 16 + lr) * 32 + lg * 8];
#pragma unroll
    for (int n = 0; n < 4; ++n) bv[n] = *(const bf16x8*)&Bs[(wc + n * 16 + lr) * 32 + lg * 8];
#pragma unroll
    for (int m = 0; m < 4; ++m)
#pragma unroll
      for (int n = 0; n < 4; ++n) acc[m][n] = mfma16(av[m], bv[n], acc[m][n]);
    __syncthreads();
  }

#pragma unroll
  for (int m = 0; m < 4; ++m) {
    int crow = row0 + wr + m * 16 + lg * 4;
#pragma unroll
    for (int n = 0; n < 4; ++n) {
      int ccol = col0 + wc + n * 16 + lr;
      int hh = ccol >> 6, dd = ccol & 63;
#pragma unroll
      for (int r = 0; r < 4; ++r) {
        int cr = crow + r;
        int bb = cr >> rpb_shift, ii = cr & mask;
        Out[(((size_t)bb * NHEAD + hh) * out_L + ii) * HDIM + dd] = f2bf(acc[m][n][r] * scale);
      }
    }
  }
}

// ---------------- ns projections ----------------
__global__ __launch_bounds__(256) void ns_proj(const float* __restrict__ nst,
                                               const float* __restrict__ Wnq, const float* __restrict__ Wnk,
                                               const float* __restrict__ Wnv,
                                               unsigned short* __restrict__ Qb, unsigned short* __restrict__ Kb,
                                               unsigned short* __restrict__ Vb) {
  const int oc = blockIdx.x, n = blockIdx.y, p = blockIdx.z;
  const float* W = p == 0 ? Wnq : p == 1 ? Wnk : Wnv;
  unsigned short* Out = p == 0 ? Qb : p == 1 ? Kb : Vb;
  const int out_L = p == 0 ? QLEN : KLEN;
  const int orow = p == 0 ? NXT + n : SEQ + n;
  const float scale = p == 0 ? QSCALE : 1.f;

  __shared__ float xs[NBATCH][DMODEL];
  __shared__ float red[NBATCH][128];
  const int tid = threadIdx.x;
  for (int idx = tid; idx < NBATCH * DMODEL; idx += 256)
    xs[idx >> 9][idx & 511] = nst[(size_t)((idx >> 9) * NSN + n) * DMODEL + (idx & 511)];
  __syncthreads();

  const int o = oc * 128 + (tid & 127);
  const int dh = tid >> 7;
  float a0 = 0.f, a1 = 0.f, a2 = 0.f, a3 = 0.f;
  const float* wp = W + (size_t)n * DMODEL * DMODEL + o;
#pragma unroll 8
  for (int d = dh * 256; d < dh * 256 + 256; ++d) {
    float wv = wp[(size_t)d * DMODEL];
    a0 += xs[0][d] * wv; a1 += xs[1][d] * wv; a2 += xs[2][d] * wv; a3 += xs[3][d] * wv;
  }
  if (dh == 1) { red[0][tid & 127] = a0; red[1][tid & 127] = a1; red[2][tid & 127] = a2; red[3][tid & 127] = a3; }
  __syncthreads();
  if (dh == 0) {
    a0 += red[0][tid & 127]; a1 += red[1][tid & 127]; a2 += red[2][tid & 127]; a3 += red[3][tid & 127];
    int hh = o >> 6, dd = o & 63;
    float v[4] = {a0, a1, a2, a3};
#pragma unroll
    for (int b = 0; b < NBATCH; ++b)
      Out[(((size_t)b * NHEAD + hh) * out_L + orow) * HDIM + dd] = f2bf(v[b] * scale);
  }
}

// ---------------- global V transpose: Vt[bh][d][kv] = V[bh][kv][d] ----------------
__global__ __launch_bounds__(256) void vtrans(const unsigned short* __restrict__ V,
                                              unsigned short* __restrict__ Vt) {
  __shared__ unsigned short t[64 * 64];
  const int tid = threadIdx.x;
  const int kv0 = blockIdx.x * 64, bh = blockIdx.y;
  const unsigned short* Vhp = V + (size_t)bh * KLEN * HDIM;
  unsigned short* Vtp = Vt + (size_t)bh * HDIM * KLEN;

#pragma unroll
  for (int i = 0; i < 2; ++i) {
    int c = i * 256 + tid;             // 512 chunks of 16B: row = kv-local, c8 = d-chunk
    int row = c >> 3, c8 = c & 7;
    int kvg = kv0 + row; if (kvg > KLEN - 1) kvg = KLEN - 1;
    int4 v4 = *(const int4*)(Vhp + (size_t)kvg * HDIM + c8 * 8);
    *(int4*)&t[row * 64 + ((c8 ^ ((row >> 3) & 7)) * 8)] = v4;
  }
  __syncthreads();
#pragma unroll
  for (int i = 0; i < 2; ++i) {
    int c = i * 256 + tid;             // 512: d row, k8 = kv-chunk
    int d = c >> 3, k8 = c & 7;
    if (kv0 + k8 * 8 <= KLEN - 8) {
      unsigned int wd[4];
#pragma unroll
      for (int jj = 0; jj < 4; ++jj) {
        int ka = k8 * 8 + jj * 2, kb2 = ka + 1;
        unsigned int lo = t[ka  * 64 + (((d >> 3) ^ ((ka  >> 3) & 7)) * 8) + (d & 7)];
        unsigned int hi = t[kb2 * 64 + (((d >> 3) ^ ((kb2 >> 3) & 7)) * 8) + (d & 7)];
        wd[jj] = lo | (hi << 16);
      }
      int4 o; o.x = wd[0]; o.y = wd[1]; o.z = wd[2]; o.w = wd[3];
      *(int4*)(Vtp + (size_t)d * KLEN + kv0 + k8 * 8) = o;
    }
  }
}

// ---------------- flash attention ----------------
// R8: back to R6 shape (4 waves, QBLK=64, 1056 blocks) but V is read from global
// Vtg directly (no Vs tile) -> LDS 24KB -> ~6 blocks/CU. waves_per_eu(2,5) gives a
// ~102-VGPR budget so the 8 in-flight V loads can't trigger the R3-style spill.
// Keeps: K DMA double-buffer + chunk swizzle, DPP max, exp2 domain, m-bias C-seed,
// ones-MFMA row-sum.
__global__ __launch_bounds__(256)
__attribute__((amdgpu_waves_per_eu(2, 5)))
void attn_kernel(const unsigned short* __restrict__ Qb,
                 const unsigned short* __restrict__ Kb,
                 const unsigned short* __restrict__ Vtg,
                 unsigned short* __restrict__ Att) {
  __shared__ unsigned short Ks[2][64 * 64];   // 8 KB x2, [kv][d] swizzled
  __shared__ unsigned short Ps[4][16 * 64];   // 2 KB x4, per-wave [q][kv] swizzled

  const int tid = threadIdx.x;
  const int w = tid >> 6, l = tid & 63;
  const int lg = l >> 4, lr = l & 15;
  const int qb = 32 - (int)blockIdx.x;                 // big blocks first
  const int bh = (int)blockIdx.z * NHEAD + (int)blockIdx.y;
  const int q0 = qb * 64;
  const int base = NXT + q0;
  const int nkb = (base >> 6) + 1;

  const unsigned short* Qh = Qb + (size_t)bh * QLEN * HDIM;
  const unsigned short* Kh = Kb + (size_t)bh * KLEN * HDIM;
  const unsigned short* Vh = Vtg + (size_t)bh * HDIM * KLEN;   // [64][KLEN]

  int qrow = q0 + w * 16 + lr; if (qrow > QLEN - 1) qrow = QLEN - 1;
  const bf16x8 qa0 = *(const bf16x8*)(Qh + (size_t)qrow * HDIM + lg * 8);
  const bf16x8 qa1 = *(const bf16x8*)(Qh + (size_t)qrow * HDIM + 32 + lg * 8);

  f32x4 acc[4];
#pragma unroll
  for (int n = 0; n < 4; ++n) acc[n] = (f32x4){0.f, 0.f, 0.f, 0.f};
  float m_r[4], lsum[4];
#pragma unroll
  for (int r = 0; r < 4; ++r) { m_r[r] = 0.f; lsum[r] = 0.f; }   // m biased at 0

  const bf16x8 ones = {(short)0x3F80, (short)0x3F80, (short)0x3F80, (short)0x3F80,
                       (short)0x3F80, (short)0x3F80, (short)0x3F80, (short)0x3F80};

  // staging lane geometry (involutive chunk swizzle, rule #21); wave w stages
  // K rows w*16 .. w*16+15 (2 chunks of 8 rows)
  const int rloc = l >> 3;
  const int jsrc = ((l & 7) ^ rloc) * 8;     // swizzled source col (elems)

#define STAGE(buf, kv0s, CLAMP)                                                     \
  {                                                                                 \
    _Pragma("unroll")                                                               \
    for (int i = 0; i < 2; ++i) {                                                   \
      const int r8 = w * 16 + i * 8;                                                \
      int kr = (kv0s) + r8 + rloc;                                                  \
      if (CLAMP) kr = kr > KLEN - 1 ? KLEN - 1 : kr;                                \
      gload_lds16(Kh + (size_t)kr * HDIM + jsrc, &Ks[buf][r8 * 64]);                \
    }                                                                               \
  }

  STAGE(0, 0, false)
  __syncthreads();
  int cur = 0;

  for (int kb = 0; kb < nkb; ++kb) {
    if (kb + 1 < nkb) {                                // prefetch next K tile via DMA
      const int nv0 = (kb + 1) * 64;
      if (nv0 + 64 <= KLEN) STAGE(cur ^ 1, nv0, false)
      else                  STAGE(cur ^ 1, nv0, true)
    }

    const unsigned short* Kc = &Ks[cur][0];
    const int kv0 = kb * 64;

    // S = Q K^T - m  (C seeded with -m_r): 16 q-rows x 64 keys per wave
    const f32x4 minit = {-m_r[0], -m_r[1], -m_r[2], -m_r[3]};
    f32x4 s[4];
#pragma unroll
    for (int n = 0; n < 4; ++n) {
      const int rk = n * 16 + lr;
      const bf16x8 k0 = *(const bf16x8*)&Kc[rk * 64 + ((lg ^ (rk & 7)) * 8)];
      const bf16x8 k1 = *(const bf16x8*)&Kc[rk * 64 + (((4 + lg) ^ (rk & 7)) * 8)];
      s[n] = mfma16(qa0, k0, minit);
      s[n] = mfma16(qa1, k1, s[n]);
    }

    // issue V loads now — L2 latency (~200cy) hides under softmax below
    int vc0 = kv0 + lg * 8;      if (vc0 > KLEN - 8) vc0 = KLEN - 8;
    int vc1 = kv0 + 32 + lg * 8; if (vc1 > KLEN - 8) vc1 = KLEN - 8;
    bf16x8 vv[4][2];
#pragma unroll
    for (int n = 0; n < 4; ++n) {
      const size_t vrow = (size_t)(n * 16 + lr) * KLEN;
      vv[n][0] = *(const bf16x8*)(Vh + vrow + vc0);
      vv[n][1] = *(const bf16x8*)(Vh + vrow + vc1);
    }

    if (kb == nkb - 1) {                               // causal mask (diag tile only)
      const int qa_base = base + w * 16 + lg * 4;
#pragma unroll
      for (int n = 0; n < 4; ++n) {
        const int kc = kv0 + n * 16 + lr;
#pragma unroll
        for (int r = 0; r < 4; ++r)
          if (kc > qa_base + r) s[n][r] = -1e30f;
      }
    }

    // online softmax (exp2 domain, biased): DPP max, subs only on grow
    float rmax[4];
#pragma unroll
    for (int r = 0; r < 4; ++r)
      rmax[r] = red_max16(fmaxf(fmaxf(s[0][r], s[1][r]), fmaxf(s[2][r], s[3][r])));
    int grow = (rmax[0] > 11.5f) | (rmax[1] > 11.5f) |
               (rmax[2] > 11.5f) | (rmax[3] > 11.5f);
    if (__any(grow)) {                                 // T13 defer-max
      float dl[4];
#pragma unroll
      for (int r = 0; r < 4; ++r) {
        dl[r] = fmaxf(rmax[r], 0.f);
        float sc = exp2f(-dl[r]);
        lsum[r] *= sc; m_r[r] += dl[r];
#pragma unroll
        for (int n = 0; n < 4; ++n) acc[n][r] *= sc;
      }
#pragma unroll
      for (int n = 0; n < 4; ++n)
#pragma unroll
        for (int r = 0; r < 4; ++r) s[n][r] = exp2f(s[n][r] - dl[r]);
    } else {
#pragma unroll
      for (int n = 0; n < 4; ++n)
#pragma unroll
        for (int r = 0; r < 4; ++r) s[n][r] = exp2f(s[n][r]);
    }

    // P -> LDS (per-wave, swizzled [q][kv]), round-half-up to bf16
    unsigned short* Pw = &Ps[w][0];
#pragma unroll
    for (int n = 0; n < 4; ++n)
#pragma unroll
      for (int r = 0; r < 4; ++r) {
        unsigned int u = __float_as_uint(s[n][r]) + 0x8000u;
        const int q = lg * 4 + r;
        const int kc = n * 2 + (lr >> 3);
        Pw[q * 64 + ((kc ^ (q & 7)) * 8) + (lr & 7)] = (unsigned short)(u >> 16);
      }
    asm volatile("s_waitcnt lgkmcnt(0)" ::: "memory");
    __builtin_amdgcn_sched_barrier(0);                 // rule #18
    bf16x8 pa[2];
#pragma unroll
    for (int ks = 0; ks < 2; ++ks)
      pa[ks] = *(const bf16x8*)&Pw[lr * 64 + (((ks * 4 + lg) ^ (lr & 7)) * 8)];

    // PV (V from registers) + row-sum via ones-MFMA
    f32x4 acc_s = (f32x4){0.f, 0.f, 0.f, 0.f};
    acc_s = mfma16(pa[0], ones, acc_s);
    acc_s = mfma16(pa[1], ones, acc_s);
#pragma unroll
    for (int n = 0; n < 4; ++n) {
      acc[n] = mfma16(pa[0], vv[n][0], acc[n]);
      acc[n] = mfma16(pa[1], vv[n][1], acc[n]);
    }
#pragma unroll
    for (int r = 0; r < 4; ++r) lsum[r] += acc_s[r];

    __syncthreads();   // readers of Ks[cur] done; next tile's DMA drained
    cur ^= 1;
  }

  float inv[4];
#pragma unroll
  for (int r = 0; r < 4; ++r) inv[r] = 1.f / lsum[r];
#pragma unroll
  for (int n = 0; n < 4; ++n)
#pragma unroll
    for (int r = 0; r < 4; ++r) {
      int qi = q0 + w * 16 + lg * 4 + r;
      if (qi < QLEN)
        Att[((size_t)blockIdx.z * QLEN + qi) * DMODEL + blockIdx.y * HDIM + n * 16 + lr] =
            f2bf(acc[n][r] * inv[r]);
    }
#undef STAGE
}

// ---------------- output GEMM (unchanged) ----------------
__global__ __launch_bounds__(256) void out_gemm(const unsigned short* __restrict__ A,
                                                const unsigned short* __restrict__ W,
                                                float* __restrict__ Out) {
  __shared__ unsigned short As[128 * 32];
  __shared__ unsigned short Bs[128 * 32];
  const int tid = threadIdx.x;
  const int w = tid >> 6, l = tid & 63;
  const int lg = l >> 4, lr = l & 15;
  const int row0 = blockIdx.x * 128, col0 = blockIdx.y * 128;
  const int wr = (w >> 1) * 64, wc = (w & 1) * 64;

  f32x4 acc[4][4];
#pragma unroll
  for (int m = 0; m < 4; ++m)
#pragma unroll
    for (int n = 0; n < 4; ++n) acc[m][n] = (f32x4){0.f, 0.f, 0.f, 0.f};

  const int sr = w * 16 + (l >> 2);
  const int sc = (l & 3) * 8;

  for (int k0 = 0; k0 < 512; k0 += 32) {
#pragma unroll
    for (int i = 0; i < 2; ++i) {
      const unsigned short* gpa = A + (size_t)(row0 + sr + i * 64) * 512 + k0 + sc;
      gload_lds16(gpa, (char*)As + i * 4096 + w * 1024);
      const unsigned short* gpb = W + (size_t)(col0 + sr + i * 64) * 512 + k0 + sc;
      gload_lds16(gpb, (char*)Bs + i * 4096 + w * 1024);
    }
    __syncthreads();
    bf16x8 av[4], bv[4];
#pragma unroll
    for (int m = 0; m < 4; ++m) av[m] = *(const bf16x8*)&As[(wr + m * 16 + lr) * 32 + lg * 8];
#pragma unroll
    for (int n = 0; n < 4; ++n) bv[n] = *(const bf16x8*)&Bs[(wc + n * 16 + lr) * 32 + lg * 8];
#pragma unroll
    for (int m = 0; m < 4; ++m)
#pragma unroll
      for (int n = 0; n < 4; ++n) acc[m][n] = mfma16(av[m], bv[n], acc[m][n]);
    __syncthreads();
  }

#pragma unroll
  for (int m = 0; m < 4; ++m) {
    int crow = row0 + wr + m * 16 + lg * 4;
#pragma unroll
    for (int n = 0; n < 4; ++n) {
      int ccol = col0 + wc + n * 16 + lr;
#pragma unroll
      for (int r = 0; r < 4; ++r) {
        int cr = crow + r;
        int bb = cr / QLEN, ii = cr - bb * QLEN;
        size_t off = ii < NXT
                       ? ((size_t)bb * NXT + ii) * DMODEL + ccol
                       : (size_t)NBATCH * NXT * DMODEL + ((size_t)bb * NSN + (ii - NXT)) * DMODEL + ccol;
        Out[off] = acc[m][n][r];
      }
    }
  }
}

// ---------------- host launch ----------------
extern "C" void kernel_launch(void* const* d_in, const int* in_sizes, int n_in,
                              void* d_out, int out_size, void* d_ws, size_t ws_size,
                              hipStream_t stream) {
  const float* seq = (const float*)d_in[0];
  const float* nst = (const float*)d_in[2];
  const float* Wq  = (const float*)d_in[5];
  const float* Wk  = (const float*)d_in[6];
  const float* Wv  = (const float*)d_in[7];
  const float* nsq = (const float*)d_in[8];
  const float* nsk = (const float*)d_in[9];
  const float* nsv = (const float*)d_in[10];
  const float* Wo  = (const float*)d_in[11];
  float* out = (float*)d_out;

  // fully disjoint workspace layout (no aliasing)
  char* ws = (char*)d_ws;
  unsigned short* Xbf  = (unsigned short*)(ws);                       // 16,777,216
  unsigned short* Wqb  = (unsigned short*)(ws + 16777216);            // 524,288 x4
  unsigned short* Wkb  = Wqb + 262144;
  unsigned short* Wvb  = Wkb + 262144;
  unsigned short* Wob  = Wvb + 262144;
  unsigned short* Qbuf = (unsigned short*)(ws + 18874368);            // 8,519,680
  unsigned short* Kbuf = (unsigned short*)(ws + 27394048);            // 16,908,288
  unsigned short* Vbuf = (unsigned short*)(ws + 44302336);            // 16,908,288
  unsigned short* Att  = (unsigned short*)(ws + 61210624);            // 8,519,680
  unsigned short* Vtg  = (unsigned short*)(ws + 69730304);            // 16,908,288 -> total 86,638,592
  if (ws_size < 86638592) return;   // insufficient scratch -> visible first-call failure

  cvt_f32_bf16_v4<<<dim3(8192), dim3(256), 0, stream>>>(seq, Xbf, 2097152);
  cvt_w4<<<dim3(256, 4), dim3(256), 0, stream>>>(Wq, Wk, Wv, Wo, Wqb);
  proj_gemm<<<dim3(128, 4), dim3(256), 0, stream>>>(Xbf, Wkb, Kbuf, 12, 0, KLEN, 1.f);
  proj_gemm<<<dim3(128, 4), dim3(256), 0, stream>>>(Xbf, Wvb, Vbuf, 12, 0, KLEN, 1.f);
  proj_gemm<<<dim3(64, 4), dim3(256), 0, stream>>>(Xbf, Wqb, Qbuf, 11, 2048, QLEN, QSCALE);
  ns_proj<<<dim3(4, 32, 3), dim3(256), 0, stream>>>(nst, nsq, nsk, nsv, Qbuf, Kbuf, Vbuf);
  vtrans<<<dim3(65, 32), dim3(256), 0, stream>>>(Vbuf, Vtg);
  attn_kernel<<<dim3(33, 8, 4), dim3(256), 0, stream>>>(Qbuf, Kbuf, Vtg, Att);
  out_gemm<<<dim3(65, 4), dim3(256), 0, stream>>>(Att, Wob, out);
}

// Round 9
// 254.924 us; speedup vs baseline: 1.3843x; 1.3843x over previous
//
#include <hip/hip_runtime.h>

// ---------------- problem constants ----------------
#define NBATCH 4
#define SEQ    4096
#define DMODEL 512
#define NHEAD  8
#define HDIM   64
#define NSN    32
#define NXT    2048
#define QLEN   2080   // NXT + NSN
#define KLEN   4128   // SEQ + NSN

using bf16x8 = __attribute__((ext_vector_type(8))) short;
using f32x4  = __attribute__((ext_vector_type(4))) float;

typedef __attribute__((address_space(1))) unsigned int gu32;
typedef __attribute__((address_space(3))) unsigned int lu32;

// Q projection pre-scale: SCALE * log2(e) — softmax runs in exp2 domain
#define QSCALE 0.18033688f

__device__ __forceinline__ unsigned short f2bf(float f) {
  unsigned int u = __float_as_uint(f);
  u += 0x7FFF + ((u >> 16) & 1);          // RTNE
  return (unsigned short)(u >> 16);
}

__device__ __forceinline__ f32x4 mfma16(bf16x8 a, bf16x8 b, f32x4 c) {
  return __builtin_amdgcn_mfma_f32_16x16x32_bf16(a, b, c, 0, 0, 0);
}

__device__ __forceinline__ void gload_lds16(const void* g, void* lds_base) {
  __builtin_amdgcn_global_load_lds((const gu32*)g, (lu32*)lds_base, 16, 0, 0);
}

__device__ __forceinline__ unsigned int cvt_pk_bf16(float lo, float hi) {
  unsigned int r;
  asm("v_cvt_pk_bf16_f32 %0, %1, %2" : "=v"(r) : "v"(lo), "v"(hi));
  return r;
}

// ---------------- fp32 -> bf16 converts ----------------
__global__ __launch_bounds__(256) void cvt_f32_bf16_v4(const float* __restrict__ src,
                                                       unsigned short* __restrict__ dst, int n4) {
  int i = blockIdx.x * 256 + threadIdx.x;
  if (i >= n4) return;
  float4 v = reinterpret_cast<const float4*>(src)[i];
  ushort4 r;
  r.x = f2bf(v.x); r.y = f2bf(v.y); r.z = f2bf(v.z); r.w = f2bf(v.w);
  reinterpret_cast<ushort4*>(dst)[i] = r;
}

__global__ __launch_bounds__(256) void cvt_w4(const float* __restrict__ a, const float* __restrict__ b,
                                              const float* __restrict__ c, const float* __restrict__ d,
                                              unsigned short* __restrict__ dst) {
  const float* s = blockIdx.y == 0 ? a : blockIdx.y == 1 ? b : blockIdx.y == 2 ? c : d;
  int i = blockIdx.x * 256 + threadIdx.x;   // 65536 float4 per matrix
  float4 v = reinterpret_cast<const float4*>(s)[i];
  ushort4 r;
  r.x = f2bf(v.x); r.y = f2bf(v.y); r.z = f2bf(v.z); r.w = f2bf(v.w);
  reinterpret_cast<ushort4*>(dst)[(size_t)blockIdx.y * 65536 + i] = r;
}

// ---------------- seq projection GEMM (m97 structure, known-good) ----------------
__global__ __launch_bounds__(256) void proj_gemm(const unsigned short* __restrict__ X,
                                                 const unsigned short* __restrict__ W,
                                                 unsigned short* __restrict__ Out,
                                                 int rpb_shift, int row_off, int out_L, float scale) {
  __shared__ unsigned short As[128 * 32];
  __shared__ unsigned short Bs[128 * 32];
  const int tid = threadIdx.x;
  const int w = tid >> 6, l = tid & 63;
  const int lg = l >> 4, lr = l & 15;
  const int row0 = blockIdx.x * 128, col0 = blockIdx.y * 128;
  const int wr = (w >> 1) * 64, wc = (w & 1) * 64;
  const int mask = (1 << rpb_shift) - 1;

  f32x4 acc[4][4];
#pragma unroll
  for (int m = 0; m < 4; ++m)
#pragma unroll
    for (int n = 0; n < 4; ++n) acc[m][n] = (f32x4){0.f, 0.f, 0.f, 0.f};

  const int sr = w * 16 + (l >> 2);
  const int sc = (l & 3) * 8;

  for (int k0 = 0; k0 < 512; k0 += 32) {
#pragma unroll
    for (int i = 0; i < 2; ++i) {
      int gr = row0 + sr + i * 64;
      int xrow = ((gr >> rpb_shift) << 12) + row_off + (gr & mask);
      const unsigned short* gpa = X + (size_t)xrow * 512 + k0 + sc;
      gload_lds16(gpa, (char*)As + i * 4096 + w * 1024);
      const unsigned short* gpb = W + (size_t)(col0 + sr + i * 64) * 512 + k0 + sc;
      gload_lds16(gpb, (char*)Bs + i * 4096 + w * 1024);
    }
    __syncthreads();
    bf16x8 av[4], bv[4];
#pragma unroll
    for (int m = 0; m < 4; ++m) av[m] = *(const bf16x8*)&As[(wr + m * 16 + lr) * 32 + lg * 8];
#pragma unroll
    for (int n = 0; n < 4; ++n) bv[n] = *(const bf16x8*)&Bs[(wc + n * 16 + lr) * 32 + lg * 8];
#pragma unroll
    for (int m = 0; m < 4; ++m)
#pragma unroll
      for (int n = 0; n < 4; ++n) acc[m][n] = mfma16(av[m], bv[n], acc[m][n]);
    __syncthreads();
  }

#pragma unroll
  for (int m = 0; m < 4; ++m) {
    int crow = row0 + wr + m * 16 + lg * 4;
#pragma unroll
    for (int n = 0; n < 4; ++n) {
      int ccol = col0 + wc + n * 16 + lr;
      int hh = ccol >> 6, dd = ccol & 63;
#pragma unroll
      for (int r = 0; r < 4; ++r) {
        int cr = crow + r;
        int bb = cr >> rpb_shift, ii = cr & mask;
        Out[(((size_t)bb * NHEAD + hh) * out_L + ii) * HDIM + dd] = f2bf(acc[m][n][r] * scale);
      }
    }
  }
}

// ---------------- ns projections ----------------
__global__ __launch_bounds__(256) void ns_proj(const float* __restrict__ nst,
                                               const float* __restrict__ Wnq, const float* __restrict__ Wnk,
                                               const float* __restrict__ Wnv,
                                               unsigned short* __restrict__ Qb, unsigned short* __restrict__ Kb,
                                               unsigned short* __restrict__ Vb) {
  const int oc = blockIdx.x, n = blockIdx.y, p = blockIdx.z;
  const float* W = p == 0 ? Wnq : p == 1 ? Wnk : Wnv;
  unsigned short* Out = p == 0 ? Qb : p == 1 ? Kb : Vb;
  const int out_L = p == 0 ? QLEN : KLEN;
  const int orow = p == 0 ? NXT + n : SEQ + n;
  const float scale = p == 0 ? QSCALE : 1.f;

  __shared__ float xs[NBATCH][DMODEL];
  __shared__ float red[NBATCH][128];
  const int tid = threadIdx.x;
  for (int idx = tid; idx < NBATCH * DMODEL; idx += 256)
    xs[idx >> 9][idx & 511] = nst[(size_t)((idx >> 9) * NSN + n) * DMODEL + (idx & 511)];
  __syncthreads();

  const int o = oc * 128 + (tid & 127);
  const int dh = tid >> 7;
  float a0 = 0.f, a1 = 0.f, a2 = 0.f, a3 = 0.f;
  const float* wp = W + (size_t)n * DMODEL * DMODEL + o;
#pragma unroll 8
  for (int d = dh * 256; d < dh * 256 + 256; ++d) {
    float wv = wp[(size_t)d * DMODEL];
    a0 += xs[0][d] * wv; a1 += xs[1][d] * wv; a2 += xs[2][d] * wv; a3 += xs[3][d] * wv;
  }
  if (dh == 1) { red[0][tid & 127] = a0; red[1][tid & 127] = a1; red[2][tid & 127] = a2; red[3][tid & 127] = a3; }
  __syncthreads();
  if (dh == 0) {
    a0 += red[0][tid & 127]; a1 += red[1][tid & 127]; a2 += red[2][tid & 127]; a3 += red[3][tid & 127];
    int hh = o >> 6, dd = o & 63;
    float v[4] = {a0, a1, a2, a3};
#pragma unroll
    for (int b = 0; b < NBATCH; ++b)
      Out[(((size_t)b * NHEAD + hh) * out_L + orow) * HDIM + dd] = f2bf(v[b] * scale);
  }
}

// ---------------- global V transpose: Vt[bh][d][kv] = V[bh][kv][d] ----------------
__global__ __launch_bounds__(256) void vtrans(const unsigned short* __restrict__ V,
                                              unsigned short* __restrict__ Vt) {
  __shared__ unsigned short t[64 * 64];
  const int tid = threadIdx.x;
  const int kv0 = blockIdx.x * 64, bh = blockIdx.y;
  const unsigned short* Vhp = V + (size_t)bh * KLEN * HDIM;
  unsigned short* Vtp = Vt + (size_t)bh * HDIM * KLEN;

#pragma unroll
  for (int i = 0; i < 2; ++i) {
    int c = i * 256 + tid;
    int row = c >> 3, c8 = c & 7;
    int kvg = kv0 + row; if (kvg > KLEN - 1) kvg = KLEN - 1;
    int4 v4 = *(const int4*)(Vhp + (size_t)kvg * HDIM + c8 * 8);
    *(int4*)&t[row * 64 + ((c8 ^ ((row >> 3) & 7)) * 8)] = v4;
  }
  __syncthreads();
#pragma unroll
  for (int i = 0; i < 2; ++i) {
    int c = i * 256 + tid;
    int d = c >> 3, k8 = c & 7;
    if (kv0 + k8 * 8 <= KLEN - 8) {
      unsigned int wd[4];
#pragma unroll
      for (int jj = 0; jj < 4; ++jj) {
        int ka = k8 * 8 + jj * 2, kb2 = ka + 1;
        unsigned int lo = t[ka  * 64 + (((d >> 3) ^ ((ka  >> 3) & 7)) * 8) + (d & 7)];
        unsigned int hi = t[kb2 * 64 + (((d >> 3) ^ ((kb2 >> 3) & 7)) * 8) + (d & 7)];
        wd[jj] = lo | (hi << 16);
      }
      int4 o; o.x = wd[0]; o.y = wd[1]; o.z = wd[2]; o.w = wd[3];
      *(int4*)(Vtp + (size_t)d * KLEN + kv0 + k8 * 8) = o;
    }
  }
}

// ---------------- flash attention (R9: swapped-operand, q lane-local) ----------------
// R6 skeleton (4 waves, QBLK=64, K+V LDS double-buffer, chunk swizzle) but:
// S^T = mfma(K, Q)  -> lane l owns q = l&15; kv = kv0 + n*16 + (l>>4)*4 + r.
// Softmax fully in-lane (+2 same-q shfls); m/lsum scalars. P redistributed to PV
// B-operand fragments IN REGISTERS via cvt_pk + permlane32_swap + ds_swizzle(xor16)
// (no Ps LDS buffer -> 32KB LDS = 5 blocks/CU, no lgkmcnt serialization).
// PV: acc = mfma(V^T, P); lsum via ones-MFMA (A=ones); out^T layout stored transposed.
__global__ __launch_bounds__(256) void attn_kernel(const unsigned short* __restrict__ Qb,
                                                   const unsigned short* __restrict__ Kb,
                                                   const unsigned short* __restrict__ Vtg,
                                                   unsigned short* __restrict__ Att) {
  __shared__ unsigned short Ks[2][64 * 64];   // 8 KB x2, [kv][d] swizzled
  __shared__ unsigned short Vs[2][64 * 64];   // 8 KB x2, [d][kv] swizzled

  const int tid = threadIdx.x;
  const int w = tid >> 6, l = tid & 63;
  const int lg = l >> 4, lr = l & 15;
  const bool geven = (l & 16) == 0;                    // (l>>4) even
  const int qb = 32 - (int)blockIdx.x;                 // big blocks first
  const int bh = (int)blockIdx.z * NHEAD + (int)blockIdx.y;
  const int q0 = qb * 64;
  const int base = NXT + q0;
  const int nkb = (base >> 6) + 1;

  const unsigned short* Qh = Qb + (size_t)bh * QLEN * HDIM;
  const unsigned short* Kh = Kb + (size_t)bh * KLEN * HDIM;
  const unsigned short* Vh = Vtg + (size_t)bh * HDIM * KLEN;   // [64][KLEN]

  int qrow = q0 + w * 16 + lr; if (qrow > QLEN - 1) qrow = QLEN - 1;
  const bf16x8 qa0 = *(const bf16x8*)(Qh + (size_t)qrow * HDIM + lg * 8);
  const bf16x8 qa1 = *(const bf16x8*)(Qh + (size_t)qrow * HDIM + 32 + lg * 8);

  f32x4 acc[4];
#pragma unroll
  for (int n = 0; n < 4; ++n) acc[n] = (f32x4){0.f, 0.f, 0.f, 0.f};
  float m_r = 0.f, lsum = 0.f;                         // per-lane scalars (q = l&15)

  const bf16x8 ones = {(short)0x3F80, (short)0x3F80, (short)0x3F80, (short)0x3F80,
                       (short)0x3F80, (short)0x3F80, (short)0x3F80, (short)0x3F80};

  // staging lane geometry (involutive chunk swizzle, rule #21)
  const int rloc = l >> 3;
  const int jsrc = ((l & 7) ^ rloc) * 8;

#define STAGE(buf, kv0s, CLAMP)                                                     \
  {                                                                                 \
    _Pragma("unroll")                                                               \
    for (int i = 0; i < 2; ++i) {                                                   \
      const int r8 = (w * 2 + i) * 8;                                               \
      int kr = (kv0s) + r8 + rloc;                                                  \
      if (CLAMP) kr = kr > KLEN - 1 ? KLEN - 1 : kr;                                \
      gload_lds16(Kh + (size_t)kr * HDIM + jsrc, &Ks[buf][r8 * 64]);                \
      int vc = (kv0s) + jsrc;                                                       \
      if (CLAMP) vc = vc > KLEN - 8 ? KLEN - 8 : vc;                                \
      gload_lds16(Vh + (size_t)(r8 + rloc) * KLEN + vc, &Vs[buf][r8 * 64]);         \
    }                                                                               \
  }

  STAGE(0, 0, false)
  __syncthreads();
  int cur = 0;

  for (int kb = 0; kb < nkb; ++kb) {
    if (kb + 1 < nkb) {                                // prefetch next tile via DMA
      const int nv0 = (kb + 1) * 64;
      if (nv0 + 64 <= KLEN) STAGE(cur ^ 1, nv0, false)
      else                  STAGE(cur ^ 1, nv0, true)
    }

    const unsigned short* Kc = &Ks[cur][0];
    const unsigned short* Vc = &Vs[cur][0];

    // S^T = K Q^T - m : lane owns q=l&15; s[n][r] is kv = kv0 + n*16 + lg*4 + r
    const f32x4 minit = {-m_r, -m_r, -m_r, -m_r};
    f32x4 s[4];
#pragma unroll
    for (int n = 0; n < 4; ++n) {
      const int rk = n * 16 + lr;
      const bf16x8 k0 = *(const bf16x8*)&Kc[rk * 64 + ((lg ^ (rk & 7)) * 8)];
      const bf16x8 k1 = *(const bf16x8*)&Kc[rk * 64 + (((4 + lg) ^ (rk & 7)) * 8)];
      s[n] = mfma16(k0, qa0, minit);                   // swapped operands
      s[n] = mfma16(k1, qa1, s[n]);
    }

    if (kb == nkb - 1) {                               // causal mask (diag tile)
      const int qk_lim = base + w * 16 + lr;           // abs pos of this lane's q
      const int kv0 = kb * 64;
#pragma unroll
      for (int n = 0; n < 4; ++n)
#pragma unroll
        for (int r = 0; r < 4; ++r)
          if (kv0 + n * 16 + lg * 4 + r > qk_lim) s[n][r] = -1e30f;
    }

    // row max: in-lane over 16 values, then same-q lanes (l^16, l^32 keep l&15)
    float rmax = fmaxf(fmaxf(fmaxf(s[0][0], s[0][1]), fmaxf(s[0][2], s[0][3])),
                       fmaxf(fmaxf(s[1][0], s[1][1]), fmaxf(s[1][2], s[1][3])));
    rmax = fmaxf(rmax, fmaxf(fmaxf(fmaxf(s[2][0], s[2][1]), fmaxf(s[2][2], s[2][3])),
                             fmaxf(fmaxf(s[3][0], s[3][1]), fmaxf(s[3][2], s[3][3]))));
    rmax = fmaxf(rmax, __shfl_xor(rmax, 16));
    rmax = fmaxf(rmax, __shfl_xor(rmax, 32));

    if (__any(rmax > 11.5f)) {                         // T13 defer-max (rare)
      float dl = fmaxf(rmax, 0.f);
      float sc = exp2f(-dl);
      lsum *= sc; m_r += dl;
#pragma unroll
      for (int n = 0; n < 4; ++n) {
        acc[n][0] *= sc; acc[n][1] *= sc; acc[n][2] *= sc; acc[n][3] *= sc;
#pragma unroll
        for (int r = 0; r < 4; ++r) s[n][r] = exp2f(s[n][r] - dl);
      }
    } else {
#pragma unroll
      for (int n = 0; n < 4; ++n)
#pragma unroll
        for (int r = 0; r < 4; ++r) s[n][r] = exp2f(s[n][r]);
    }

    // ---- P redistribution to PV B-operand frags (registers only) ----
    // wpk[n][j2] = bf16pair(s[n][2j2], s[n][2j2+1])  (kv ascending, lo word first)
    unsigned int wpk[4][2];
#pragma unroll
    for (int n = 0; n < 4; ++n) {
      wpk[n][0] = cvt_pk_bf16(s[n][0], s[n][1]);
      wpk[n][1] = cvt_pk_bf16(s[n][2], s[n][3]);
    }
    bf16x8 pb[2];
#pragma unroll
    for (int ks = 0; ks < 2; ++ks) {
      unsigned int A0 = wpk[2 * ks][0], B0 = wpk[2 * ks + 1][0];
      unsigned int A1 = wpk[2 * ks][1], B1 = wpk[2 * ks + 1][1];
      asm("v_permlane32_swap_b32 %0, %1" : "+v"(A0), "+v"(B0));
      asm("v_permlane32_swap_b32 %0, %1" : "+v"(A1), "+v"(B1));
      unsigned int sA0 = __builtin_amdgcn_ds_swizzle(A0, 0x401F);  // lane ^16
      unsigned int sA1 = __builtin_amdgcn_ds_swizzle(A1, 0x401F);
      unsigned int sB0 = __builtin_amdgcn_ds_swizzle(B0, 0x401F);
      unsigned int sB1 = __builtin_amdgcn_ds_swizzle(B1, 0x401F);
      int4 words;
      words.x = geven ? A0 : sB0;   // kv 8g+0,1
      words.y = geven ? A1 : sB1;   // kv 8g+2,3
      words.z = geven ? sA0 : B0;   // kv 8g+4,5
      words.w = geven ? sA1 : B1;   // kv 8g+6,7
      pb[ks] = *(bf16x8*)&words;    // B-frag: P[kv=32ks+(l>>4)*8+j][q=l&15]
    }

    // lsum via ones-MFMA (A=ones): D[.][q] = sum_kv P[kv][q]
    f32x4 acc_s = (f32x4){0.f, 0.f, 0.f, 0.f};
    acc_s = mfma16(ones, pb[0], acc_s);
    acc_s = mfma16(ones, pb[1], acc_s);
    lsum += acc_s[0];

    // PV: out^T[d][q] += V^T[d][kv] P[kv][q]  (Vs reads identical to R6)
#pragma unroll
    for (int n = 0; n < 4; ++n) {
      const int rv = n * 16 + lr;
#pragma unroll
      for (int ks = 0; ks < 2; ++ks) {
        const bf16x8 vv = *(const bf16x8*)&Vc[rv * 64 + (((ks * 4 + lg) ^ (rv & 7)) * 8)];
        acc[n] = mfma16(vv, pb[ks], acc[n]);           // swapped operands
      }
    }

    __syncthreads();   // readers of buf[cur] done; next tile's DMA drained
    cur ^= 1;
  }

  // store: acc[n][r] = out[q = q0+w*16+lr][d = n*16 + lg*4 + r]
  const int qi = q0 + w * 16 + lr;
  if (qi < QLEN) {
    const float inv = 1.f / lsum;
    unsigned short* orow =
        Att + ((size_t)blockIdx.z * QLEN + qi) * DMODEL + blockIdx.y * HDIM;
#pragma unroll
    for (int n = 0; n < 4; ++n)
#pragma unroll
      for (int r = 0; r < 4; ++r)
        orow[n * 16 + lg * 4 + r] = f2bf(acc[n][r] * inv);
  }
#undef STAGE
}

// ---------------- output GEMM (unchanged) ----------------
__global__ __launch_bounds__(256) void out_gemm(const unsigned short* __restrict__ A,
                                                const unsigned short* __restrict__ W,
                                                float* __restrict__ Out) {
  __shared__ unsigned short As[128 * 32];
  __shared__ unsigned short Bs[128 * 32];
  const int tid = threadIdx.x;
  const int w = tid >> 6, l = tid & 63;
  const int lg = l >> 4, lr = l & 15;
  const int row0 = blockIdx.x * 128, col0 = blockIdx.y * 128;
  const int wr = (w >> 1) * 64, wc = (w & 1) * 64;

  f32x4 acc[4][4];
#pragma unroll
  for (int m = 0; m < 4; ++m)
#pragma unroll
    for (int n = 0; n < 4; ++n) acc[m][n] = (f32x4){0.f, 0.f, 0.f, 0.f};

  const int sr = w * 16 + (l >> 2);
  const int sc = (l & 3) * 8;

  for (int k0 = 0; k0 < 512; k0 += 32) {
#pragma unroll
    for (int i = 0; i < 2; ++i) {
      const unsigned short* gpa = A + (size_t)(row0 + sr + i * 64) * 512 + k0 + sc;
      gload_lds16(gpa, (char*)As + i * 4096 + w * 1024);
      const unsigned short* gpb = W + (size_t)(col0 + sr + i * 64) * 512 + k0 + sc;
      gload_lds16(gpb, (char*)Bs + i * 4096 + w * 1024);
    }
    __syncthreads();
    bf16x8 av[4], bv[4];
#pragma unroll
    for (int m = 0; m < 4; ++m) av[m] = *(const bf16x8*)&As[(wr + m * 16 + lr) * 32 + lg * 8];
#pragma unroll
    for (int n = 0; n < 4; ++n) bv[n] = *(const bf16x8*)&Bs[(wc + n * 16 + lr) * 32 + lg * 8];
#pragma unroll
    for (int m = 0; m < 4; ++m)
#pragma unroll
      for (int n = 0; n < 4; ++n) acc[m][n] = mfma16(av[m], bv[n], acc[m][n]);
    __syncthreads();
  }

#pragma unroll
  for (int m = 0; m < 4; ++m) {
    int crow = row0 + wr + m * 16 + lg * 4;
#pragma unroll
    for (int n = 0; n < 4; ++n) {
      int ccol = col0 + wc + n * 16 + lr;
#pragma unroll
      for (int r = 0; r < 4; ++r) {
        int cr = crow + r;
        int bb = cr / QLEN, ii = cr - bb * QLEN;
        size_t off = ii < NXT
                       ? ((size_t)bb * NXT + ii) * DMODEL + ccol
                       : (size_t)NBATCH * NXT * DMODEL + ((size_t)bb * NSN + (ii - NXT)) * DMODEL + ccol;
        Out[off] = acc[m][n][r];
      }
    }
  }
}

// ---------------- host launch ----------------
extern "C" void kernel_launch(void* const* d_in, const int* in_sizes, int n_in,
                              void* d_out, int out_size, void* d_ws, size_t ws_size,
                              hipStream_t stream) {
  const float* seq = (const float*)d_in[0];
  const float* nst = (const float*)d_in[2];
  const float* Wq  = (const float*)d_in[5];
  const float* Wk  = (const float*)d_in[6];
  const float* Wv  = (const float*)d_in[7];
  const float* nsq = (const float*)d_in[8];
  const float* nsk = (const float*)d_in[9];
  const float* nsv = (const float*)d_in[10];
  const float* Wo  = (const float*)d_in[11];
  float* out = (float*)d_out;

  // fully disjoint workspace layout (no aliasing)
  char* ws = (char*)d_ws;
  unsigned short* Xbf  = (unsigned short*)(ws);                       // 16,777,216
  unsigned short* Wqb  = (unsigned short*)(ws + 16777216);            // 524,288 x4
  unsigned short* Wkb  = Wqb + 262144;
  unsigned short* Wvb  = Wkb + 262144;
  unsigned short* Wob  = Wvb + 262144;
  unsigned short* Qbuf = (unsigned short*)(ws + 18874368);            // 8,519,680
  unsigned short* Kbuf = (unsigned short*)(ws + 27394048);            // 16,908,288
  unsigned short* Vbuf = (unsigned short*)(ws + 44302336);            // 16,908,288
  unsigned short* Att  = (unsigned short*)(ws + 61210624);            // 8,519,680
  unsigned short* Vtg  = (unsigned short*)(ws + 69730304);            // 16,908,288 -> total 86,638,592
  if (ws_size < 86638592) return;   // insufficient scratch -> visible first-call failure

  cvt_f32_bf16_v4<<<dim3(8192), dim3(256), 0, stream>>>(seq, Xbf, 2097152);
  cvt_w4<<<dim3(256, 4), dim3(256), 0, stream>>>(Wq, Wk, Wv, Wo, Wqb);
  proj_gemm<<<dim3(128, 4), dim3(256), 0, stream>>>(Xbf, Wkb, Kbuf, 12, 0, KLEN, 1.f);
  proj_gemm<<<dim3(128, 4), dim3(256), 0, stream>>>(Xbf, Wvb, Vbuf, 12, 0, KLEN, 1.f);
  proj_gemm<<<dim3(64, 4), dim3(256), 0, stream>>>(Xbf, Wqb, Qbuf, 11, 2048, QLEN, QSCALE);
  ns_proj<<<dim3(4, 32, 3), dim3(256), 0, stream>>>(nst, nsq, nsk, nsv, Qbuf, Kbuf, Vbuf);
  vtrans<<<dim3(65, 32), dim3(256), 0, stream>>>(Vbuf, Vtg);
  attn_kernel<<<dim3(33, 8, 4), dim3(256), 0, stream>>>(Qbuf, Kbuf, Vtg, Att);
  out_gemm<<<dim3(65, 4), dim3(256), 0, stream>>>(Att, Wob, out);
}

// Round 10
// 233.352 us; speedup vs baseline: 1.5123x; 1.0924x over previous
//
#include <hip/hip_runtime.h>

// ---------------- problem constants ----------------
#define NBATCH 4
#define SEQ    4096
#define DMODEL 512
#define NHEAD  8
#define HDIM   64
#define NSN    32
#define NXT    2048
#define QLEN   2080   // NXT + NSN
#define KLEN   4128   // SEQ + NSN

using bf16x8 = __attribute__((ext_vector_type(8))) short;
using f32x4  = __attribute__((ext_vector_type(4))) float;

typedef __attribute__((address_space(1))) unsigned int gu32;
typedef __attribute__((address_space(3))) unsigned int lu32;

// Q projection pre-scale: SCALE * log2(e) — softmax runs in exp2 domain
#define QSCALE 0.18033688f

__device__ __forceinline__ unsigned short f2bf(float f) {
  unsigned int u = __float_as_uint(f);
  u += 0x7FFF + ((u >> 16) & 1);          // RTNE
  return (unsigned short)(u >> 16);
}

__device__ __forceinline__ float bf2f(unsigned short u) {
  return __uint_as_float((unsigned int)u << 16);
}

__device__ __forceinline__ f32x4 mfma16(bf16x8 a, bf16x8 b, f32x4 c) {
  return __builtin_amdgcn_mfma_f32_16x16x32_bf16(a, b, c, 0, 0, 0);
}

__device__ __forceinline__ void gload_lds16(const void* g, void* lds_base) {
  __builtin_amdgcn_global_load_lds((const gu32*)g, (lu32*)lds_base, 16, 0, 0);
}

__device__ __forceinline__ unsigned int cvt_pk_bf16(float lo, float hi) {
  unsigned int r;
  asm("v_cvt_pk_bf16_f32 %0, %1, %2" : "=v"(r) : "v"(lo), "v"(hi));
  return r;
}

// ---------------- fp32 -> bf16 converts ----------------
__global__ __launch_bounds__(256) void cvt_f32_bf16_v4(const float* __restrict__ src,
                                                       unsigned short* __restrict__ dst, int n4) {
  int i = blockIdx.x * 256 + threadIdx.x;
  if (i >= n4) return;
  float4 v = reinterpret_cast<const float4*>(src)[i];
  ushort4 r;
  r.x = f2bf(v.x); r.y = f2bf(v.y); r.z = f2bf(v.z); r.w = f2bf(v.w);
  reinterpret_cast<ushort4*>(dst)[i] = r;
}

__global__ __launch_bounds__(256) void cvt_w4(const float* __restrict__ a, const float* __restrict__ b,
                                              const float* __restrict__ c, const float* __restrict__ d,
                                              unsigned short* __restrict__ dst) {
  const float* s = blockIdx.y == 0 ? a : blockIdx.y == 1 ? b : blockIdx.y == 2 ? c : d;
  int i = blockIdx.x * 256 + threadIdx.x;   // 65536 float4 per matrix
  float4 v = reinterpret_cast<const float4*>(s)[i];
  ushort4 r;
  r.x = f2bf(v.x); r.y = f2bf(v.y); r.z = f2bf(v.z); r.w = f2bf(v.w);
  reinterpret_cast<ushort4*>(dst)[(size_t)blockIdx.y * 65536 + i] = r;
}

// ---------------- seq projection GEMM (m97 structure, known-good) ----------------
__global__ __launch_bounds__(256) void proj_gemm(const unsigned short* __restrict__ X,
                                                 const unsigned short* __restrict__ W,
                                                 unsigned short* __restrict__ Out,
                                                 int rpb_shift, int row_off, int out_L, float scale) {
  __shared__ unsigned short As[128 * 32];
  __shared__ unsigned short Bs[128 * 32];
  const int tid = threadIdx.x;
  const int w = tid >> 6, l = tid & 63;
  const int lg = l >> 4, lr = l & 15;
  const int row0 = blockIdx.x * 128, col0 = blockIdx.y * 128;
  const int wr = (w >> 1) * 64, wc = (w & 1) * 64;
  const int mask = (1 << rpb_shift) - 1;

  f32x4 acc[4][4];
#pragma unroll
  for (int m = 0; m < 4; ++m)
#pragma unroll
    for (int n = 0; n < 4; ++n) acc[m][n] = (f32x4){0.f, 0.f, 0.f, 0.f};

  const int sr = w * 16 + (l >> 2);
  const int sc = (l & 3) * 8;

  for (int k0 = 0; k0 < 512; k0 += 32) {
#pragma unroll
    for (int i = 0; i < 2; ++i) {
      int gr = row0 + sr + i * 64;
      int xrow = ((gr >> rpb_shift) << 12) + row_off + (gr & mask);
      const unsigned short* gpa = X + (size_t)xrow * 512 + k0 + sc;
      gload_lds16(gpa, (char*)As + i * 4096 + w * 1024);
      const unsigned short* gpb = W + (size_t)(col0 + sr + i * 64) * 512 + k0 + sc;
      gload_lds16(gpb, (char*)Bs + i * 4096 + w * 1024);
    }
    __syncthreads();
    bf16x8 av[4], bv[4];
#pragma unroll
    for (int m = 0; m < 4; ++m) av[m] = *(const bf16x8*)&As[(wr + m * 16 + lr) * 32 + lg * 8];
#pragma unroll
    for (int n = 0; n < 4; ++n) bv[n] = *(const bf16x8*)&Bs[(wc + n * 16 + lr) * 32 + lg * 8];
#pragma unroll
    for (int m = 0; m < 4; ++m)
#pragma unroll
      for (int n = 0; n < 4; ++n) acc[m][n] = mfma16(av[m], bv[n], acc[m][n]);
    __syncthreads();
  }

#pragma unroll
  for (int m = 0; m < 4; ++m) {
    int crow = row0 + wr + m * 16 + lg * 4;
#pragma unroll
    for (int n = 0; n < 4; ++n) {
      int ccol = col0 + wc + n * 16 + lr;
      int hh = ccol >> 6, dd = ccol & 63;
#pragma unroll
      for (int r = 0; r < 4; ++r) {
        int cr = crow + r;
        int bb = cr >> rpb_shift, ii = cr & mask;
        Out[(((size_t)bb * NHEAD + hh) * out_L + ii) * HDIM + dd] = f2bf(acc[m][n][r] * scale);
      }
    }
  }
}

// ---------------- ns projections ----------------
__global__ __launch_bounds__(256) void ns_proj(const float* __restrict__ nst,
                                               const float* __restrict__ Wnq, const float* __restrict__ Wnk,
                                               const float* __restrict__ Wnv,
                                               unsigned short* __restrict__ Qb, unsigned short* __restrict__ Kb,
                                               unsigned short* __restrict__ Vb) {
  const int oc = blockIdx.x, n = blockIdx.y, p = blockIdx.z;
  const float* W = p == 0 ? Wnq : p == 1 ? Wnk : Wnv;
  unsigned short* Out = p == 0 ? Qb : p == 1 ? Kb : Vb;
  const int out_L = p == 0 ? QLEN : KLEN;
  const int orow = p == 0 ? NXT + n : SEQ + n;
  const float scale = p == 0 ? QSCALE : 1.f;

  __shared__ float xs[NBATCH][DMODEL];
  __shared__ float red[NBATCH][128];
  const int tid = threadIdx.x;
  for (int idx = tid; idx < NBATCH * DMODEL; idx += 256)
    xs[idx >> 9][idx & 511] = nst[(size_t)((idx >> 9) * NSN + n) * DMODEL + (idx & 511)];
  __syncthreads();

  const int o = oc * 128 + (tid & 127);
  const int dh = tid >> 7;
  float a0 = 0.f, a1 = 0.f, a2 = 0.f, a3 = 0.f;
  const float* wp = W + (size_t)n * DMODEL * DMODEL + o;
#pragma unroll 8
  for (int d = dh * 256; d < dh * 256 + 256; ++d) {
    float wv = wp[(size_t)d * DMODEL];
    a0 += xs[0][d] * wv; a1 += xs[1][d] * wv; a2 += xs[2][d] * wv; a3 += xs[3][d] * wv;
  }
  if (dh == 1) { red[0][tid & 127] = a0; red[1][tid & 127] = a1; red[2][tid & 127] = a2; red[3][tid & 127] = a3; }
  __syncthreads();
  if (dh == 0) {
    a0 += red[0][tid & 127]; a1 += red[1][tid & 127]; a2 += red[2][tid & 127]; a3 += red[3][tid & 127];
    int hh = o >> 6, dd = o & 63;
    float v[4] = {a0, a1, a2, a3};
#pragma unroll
    for (int b = 0; b < NBATCH; ++b)
      Out[(((size_t)b * NHEAD + hh) * out_L + orow) * HDIM + dd] = f2bf(v[b] * scale);
  }
}

// ---------------- global V transpose: Vt[bh][d][kv] = V[bh][kv][d] ----------------
__global__ __launch_bounds__(256) void vtrans(const unsigned short* __restrict__ V,
                                              unsigned short* __restrict__ Vt) {
  __shared__ unsigned short t[64 * 64];
  const int tid = threadIdx.x;
  const int kv0 = blockIdx.x * 64, bh = blockIdx.y;
  const unsigned short* Vhp = V + (size_t)bh * KLEN * HDIM;
  unsigned short* Vtp = Vt + (size_t)bh * HDIM * KLEN;

#pragma unroll
  for (int i = 0; i < 2; ++i) {
    int c = i * 256 + tid;
    int row = c >> 3, c8 = c & 7;
    int kvg = kv0 + row; if (kvg > KLEN - 1) kvg = KLEN - 1;
    int4 v4 = *(const int4*)(Vhp + (size_t)kvg * HDIM + c8 * 8);
    *(int4*)&t[row * 64 + ((c8 ^ ((row >> 3) & 7)) * 8)] = v4;
  }
  __syncthreads();
#pragma unroll
  for (int i = 0; i < 2; ++i) {
    int c = i * 256 + tid;
    int d = c >> 3, k8 = c & 7;
    if (kv0 + k8 * 8 <= KLEN - 8) {
      unsigned int wd[4];
#pragma unroll
      for (int jj = 0; jj < 4; ++jj) {
        int ka = k8 * 8 + jj * 2, kb2 = ka + 1;
        unsigned int lo = t[ka  * 64 + (((d >> 3) ^ ((ka  >> 3) & 7)) * 8) + (d & 7)];
        unsigned int hi = t[kb2 * 64 + (((d >> 3) ^ ((kb2 >> 3) & 7)) * 8) + (d & 7)];
        wd[jj] = lo | (hi << 16);
      }
      int4 o; o.x = wd[0]; o.y = wd[1]; o.z = wd[2]; o.w = wd[3];
      *(int4*)(Vtp + (size_t)d * KLEN + kv0 + k8 * 8) = o;
    }
  }
}

// ---------------- flash attention (R10: split-K x2, single-buffer LDS) ----------------
// Grid (66, 8, 4): blockIdx.x = (qb,split); each split covers a DISJOINT half of the
// kv-tile range -> 2112 blocks (8.25/CU) vs R9's 1056 (grid was the occupancy limit).
// LDS single-buffered 16KB -> 8 blocks/CU capacity; TLP covers the staging wait
// (m97 lesson: implicit wave overlap beats explicit dbuf).
// Partial (unnormalized acc bf16, {m,lsum} fp32) per split; attn_combine merges.
// In-tile machinery identical to R9 (swapped-operand, in-reg P redistribution).
__global__ __launch_bounds__(256) void attn_kernel(const unsigned short* __restrict__ Qb,
                                                   const unsigned short* __restrict__ Kb,
                                                   const unsigned short* __restrict__ Vtg,
                                                   unsigned short* __restrict__ Po,
                                                   float2* __restrict__ Pml) {
  __shared__ unsigned short Ks[64 * 64];   // 8 KB [kv][d] swizzled
  __shared__ unsigned short Vs[64 * 64];   // 8 KB [d][kv] swizzled

  const int tid = threadIdx.x;
  const int w = tid >> 6, l = tid & 63;
  const int lg = l >> 4, lr = l & 15;
  const bool geven = (l & 16) == 0;
  const int bx = (int)blockIdx.x;
  const int qb = 32 - (bx >> 1);                       // big q-blocks first
  const int sp = bx & 1;
  const int bh = (int)blockIdx.z * NHEAD + (int)blockIdx.y;
  const int q0 = qb * 64;
  const int base = NXT + q0;
  const int nkb = (base >> 6) + 1;                     // total tiles for this q-block
  const int h0 = (nkb + 1) >> 1;                       // split0 gets the bigger half
  const int t0 = sp ? h0 : 0;
  const int t1 = sp ? nkb : h0;

  const unsigned short* Qh = Qb + (size_t)bh * QLEN * HDIM;
  const unsigned short* Kh = Kb + (size_t)bh * KLEN * HDIM;
  const unsigned short* Vh = Vtg + (size_t)bh * HDIM * KLEN;   // [64][KLEN]

  int qrow = q0 + w * 16 + lr; if (qrow > QLEN - 1) qrow = QLEN - 1;
  const bf16x8 qa0 = *(const bf16x8*)(Qh + (size_t)qrow * HDIM + lg * 8);
  const bf16x8 qa1 = *(const bf16x8*)(Qh + (size_t)qrow * HDIM + 32 + lg * 8);

  f32x4 acc[4];
#pragma unroll
  for (int n = 0; n < 4; ++n) acc[n] = (f32x4){0.f, 0.f, 0.f, 0.f};
  float m_r = 0.f, lsum = 0.f;                         // per-lane scalars (q = l&15)

  const bf16x8 ones = {(short)0x3F80, (short)0x3F80, (short)0x3F80, (short)0x3F80,
                       (short)0x3F80, (short)0x3F80, (short)0x3F80, (short)0x3F80};

  // staging lane geometry (involutive chunk swizzle, rule #21)
  const int rloc = l >> 3;
  const int jsrc = ((l & 7) ^ rloc) * 8;

  for (int kb = t0; kb < t1; ++kb) {
    const int kv0 = kb * 64;
    // stage this tile (single buffer): waves cooperatively DMA K and V
    if (kv0 + 64 <= KLEN) {
#pragma unroll
      for (int i = 0; i < 2; ++i) {
        const int r8 = (w * 2 + i) * 8;
        gload_lds16(Kh + (size_t)(kv0 + r8 + rloc) * HDIM + jsrc, &Ks[r8 * 64]);
        gload_lds16(Vh + (size_t)(r8 + rloc) * KLEN + kv0 + jsrc, &Vs[r8 * 64]);
      }
    } else {
#pragma unroll
      for (int i = 0; i < 2; ++i) {
        const int r8 = (w * 2 + i) * 8;
        int kr = kv0 + r8 + rloc; if (kr > KLEN - 1) kr = KLEN - 1;
        gload_lds16(Kh + (size_t)kr * HDIM + jsrc, &Ks[r8 * 64]);
        int vc = kv0 + jsrc; if (vc > KLEN - 8) vc = KLEN - 8;
        gload_lds16(Vh + (size_t)(r8 + rloc) * KLEN + vc, &Vs[r8 * 64]);
      }
    }
    __syncthreads();                                   // DMA drained, tile ready

    // S^T = K Q^T - m : lane owns q=l&15; s[n][r] is kv = kv0 + n*16 + lg*4 + r
    const f32x4 minit = {-m_r, -m_r, -m_r, -m_r};
    f32x4 s[4];
#pragma unroll
    for (int n = 0; n < 4; ++n) {
      const int rk = n * 16 + lr;
      const bf16x8 k0 = *(const bf16x8*)&Ks[rk * 64 + ((lg ^ (rk & 7)) * 8)];
      const bf16x8 k1 = *(const bf16x8*)&Ks[rk * 64 + (((4 + lg) ^ (rk & 7)) * 8)];
      s[n] = mfma16(k0, qa0, minit);                   // swapped operands
      s[n] = mfma16(k1, qa1, s[n]);
    }

    if (kb == nkb - 1) {                               // causal mask (diag tile, split1)
      const int qk_lim = base + w * 16 + lr;
#pragma unroll
      for (int n = 0; n < 4; ++n)
#pragma unroll
        for (int r = 0; r < 4; ++r)
          if (kv0 + n * 16 + lg * 4 + r > qk_lim) s[n][r] = -1e30f;
    }

    // local (in-lane) max is enough for the defer check: global max > thr
    // iff some lane's local max > thr, and __any is wave-wide.
    float rl = fmaxf(fmaxf(fmaxf(s[0][0], s[0][1]), fmaxf(s[0][2], s[0][3])),
                     fmaxf(fmaxf(s[1][0], s[1][1]), fmaxf(s[1][2], s[1][3])));
    rl = fmaxf(rl, fmaxf(fmaxf(fmaxf(s[2][0], s[2][1]), fmaxf(s[2][2], s[2][3])),
                         fmaxf(fmaxf(s[3][0], s[3][1]), fmaxf(s[3][2], s[3][3]))));

    if (__any(rl > 11.5f)) {                           // T13 defer-max (rare branch)
      float rmax = fmaxf(rl, __shfl_xor(rl, 16));      // full cross-q-lane max
      rmax = fmaxf(rmax, __shfl_xor(rmax, 32));
      float dl = fmaxf(rmax, 0.f);
      float sc = exp2f(-dl);
      lsum *= sc; m_r += dl;
#pragma unroll
      for (int n = 0; n < 4; ++n) {
        acc[n][0] *= sc; acc[n][1] *= sc; acc[n][2] *= sc; acc[n][3] *= sc;
#pragma unroll
        for (int r = 0; r < 4; ++r) s[n][r] = exp2f(s[n][r] - dl);
      }
    } else {
#pragma unroll
      for (int n = 0; n < 4; ++n)
#pragma unroll
        for (int r = 0; r < 4; ++r) s[n][r] = exp2f(s[n][r]);
    }

    // ---- P redistribution to PV B-operand frags (registers only, as R9) ----
    unsigned int wpk[4][2];
#pragma unroll
    for (int n = 0; n < 4; ++n) {
      wpk[n][0] = cvt_pk_bf16(s[n][0], s[n][1]);
      wpk[n][1] = cvt_pk_bf16(s[n][2], s[n][3]);
    }
    bf16x8 pb[2];
#pragma unroll
    for (int ks = 0; ks < 2; ++ks) {
      unsigned int A0 = wpk[2 * ks][0], B0 = wpk[2 * ks + 1][0];
      unsigned int A1 = wpk[2 * ks][1], B1 = wpk[2 * ks + 1][1];
      asm("v_permlane32_swap_b32 %0, %1" : "+v"(A0), "+v"(B0));
      asm("v_permlane32_swap_b32 %0, %1" : "+v"(A1), "+v"(B1));
      unsigned int sA0 = __builtin_amdgcn_ds_swizzle(A0, 0x401F);  // lane ^16
      unsigned int sA1 = __builtin_amdgcn_ds_swizzle(A1, 0x401F);
      unsigned int sB0 = __builtin_amdgcn_ds_swizzle(B0, 0x401F);
      unsigned int sB1 = __builtin_amdgcn_ds_swizzle(B1, 0x401F);
      int4 words;
      words.x = geven ? A0 : sB0;
      words.y = geven ? A1 : sB1;
      words.z = geven ? sA0 : B0;
      words.w = geven ? sA1 : B1;
      pb[ks] = *(bf16x8*)&words;    // B-frag: P[kv=32ks+(l>>4)*8+j][q=l&15]
    }

    // lsum via ones-MFMA (A=ones)
    f32x4 acc_s = (f32x4){0.f, 0.f, 0.f, 0.f};
    acc_s = mfma16(ones, pb[0], acc_s);
    acc_s = mfma16(ones, pb[1], acc_s);
    lsum += acc_s[0];

    // PV: out^T[d][q] += V^T[d][kv] P[kv][q]
#pragma unroll
    for (int n = 0; n < 4; ++n) {
      const int rv = n * 16 + lr;
#pragma unroll
      for (int ks = 0; ks < 2; ++ks) {
        const bf16x8 vv = *(const bf16x8*)&Vs[rv * 64 + (((ks * 4 + lg) ^ (rv & 7)) * 8)];
        acc[n] = mfma16(vv, pb[ks], acc[n]);
      }
    }

    __syncthreads();   // readers done before next tile's DMA overwrites
  }

  // store partials: acc[n][r] = out[q = q0+w*16+lr][d = n*16+lg*4+r] (unnormalized)
  const int qi = q0 + w * 16 + lr;
  if (qi < QLEN) {
    const size_t rowp = (size_t)(sp * 32 + bh) * QLEN + qi;
    unsigned short* po = Po + rowp * 64;
#pragma unroll
    for (int n = 0; n < 4; ++n)
#pragma unroll
      for (int r = 0; r < 4; ++r)
        po[n * 16 + lg * 4 + r] = f2bf(acc[n][r]);
    if (l < 16) Pml[rowp] = (float2){m_r, lsum};
  }
}

// ---------------- split-K combine ----------------
// grid (65, 32): bh = blockIdx.y; idx covers (qi, d-chunk of 8)
__global__ __launch_bounds__(256) void attn_combine(const unsigned short* __restrict__ Po,
                                                    const float2* __restrict__ Pml,
                                                    unsigned short* __restrict__ Att) {
  const int bh = blockIdx.y;
  const int idx = blockIdx.x * 256 + threadIdx.x;
  const int qi = idx >> 3, dc = (idx & 7) * 8;
  const size_t row = (size_t)bh * QLEN + qi;
  const float2 ml0 = Pml[row];
  const float2 ml1 = Pml[(size_t)32 * QLEN + row];
  const float mm = fmaxf(ml0.x, ml1.x);
  float s0 = exp2f(ml0.x - mm), s1 = exp2f(ml1.x - mm);
  const float inv = 1.f / (ml0.y * s0 + ml1.y * s1);
  s0 *= inv; s1 *= inv;
  const bf16x8 o0 = *(const bf16x8*)(Po + row * 64 + dc);
  const bf16x8 o1 = *(const bf16x8*)(Po + ((size_t)32 * QLEN + row) * 64 + dc);
  unsigned short out[8];
#pragma unroll
  for (int j = 0; j < 8; ++j)
    out[j] = f2bf(bf2f((unsigned short)o0[j]) * s0 + bf2f((unsigned short)o1[j]) * s1);
  const int b = bh >> 3, h = bh & 7;
  *(int4*)(Att + ((size_t)b * QLEN + qi) * DMODEL + h * HDIM + dc) = *(int4*)out;
}

// ---------------- output GEMM (unchanged) ----------------
__global__ __launch_bounds__(256) void out_gemm(const unsigned short* __restrict__ A,
                                                const unsigned short* __restrict__ W,
                                                float* __restrict__ Out) {
  __shared__ unsigned short As[128 * 32];
  __shared__ unsigned short Bs[128 * 32];
  const int tid = threadIdx.x;
  const int w = tid >> 6, l = tid & 63;
  const int lg = l >> 4, lr = l & 15;
  const int row0 = blockIdx.x * 128, col0 = blockIdx.y * 128;
  const int wr = (w >> 1) * 64, wc = (w & 1) * 64;

  f32x4 acc[4][4];
#pragma unroll
  for (int m = 0; m < 4; ++m)
#pragma unroll
    for (int n = 0; n < 4; ++n) acc[m][n] = (f32x4){0.f, 0.f, 0.f, 0.f};

  const int sr = w * 16 + (l >> 2);
  const int sc = (l & 3) * 8;

  for (int k0 = 0; k0 < 512; k0 += 32) {
#pragma unroll
    for (int i = 0; i < 2; ++i) {
      const unsigned short* gpa = A + (size_t)(row0 + sr + i * 64) * 512 + k0 + sc;
      gload_lds16(gpa, (char*)As + i * 4096 + w * 1024);
      const unsigned short* gpb = W + (size_t)(col0 + sr + i * 64) * 512 + k0 + sc;
      gload_lds16(gpb, (char*)Bs + i * 4096 + w * 1024);
    }
    __syncthreads();
    bf16x8 av[4], bv[4];
#pragma unroll
    for (int m = 0; m < 4; ++m) av[m] = *(const bf16x8*)&As[(wr + m * 16 + lr) * 32 + lg * 8];
#pragma unroll
    for (int n = 0; n < 4; ++n) bv[n] = *(const bf16x8*)&Bs[(wc + n * 16 + lr) * 32 + lg * 8];
#pragma unroll
    for (int m = 0; m < 4; ++m)
#pragma unroll
      for (int n = 0; n < 4; ++n) acc[m][n] = mfma16(av[m], bv[n], acc[m][n]);
    __syncthreads();
  }

#pragma unroll
  for (int m = 0; m < 4; ++m) {
    int crow = row0 + wr + m * 16 + lg * 4;
#pragma unroll
    for (int n = 0; n < 4; ++n) {
      int ccol = col0 + wc + n * 16 + lr;
#pragma unroll
      for (int r = 0; r < 4; ++r) {
        int cr = crow + r;
        int bb = cr / QLEN, ii = cr - bb * QLEN;
        size_t off = ii < NXT
                       ? ((size_t)bb * NXT + ii) * DMODEL + ccol
                       : (size_t)NBATCH * NXT * DMODEL + ((size_t)bb * NSN + (ii - NXT)) * DMODEL + ccol;
        Out[off] = acc[m][n][r];
      }
    }
  }
}

// ---------------- host launch ----------------
extern "C" void kernel_launch(void* const* d_in, const int* in_sizes, int n_in,
                              void* d_out, int out_size, void* d_ws, size_t ws_size,
                              hipStream_t stream) {
  const float* seq = (const float*)d_in[0];
  const float* nst = (const float*)d_in[2];
  const float* Wq  = (const float*)d_in[5];
  const float* Wk  = (const float*)d_in[6];
  const float* Wv  = (const float*)d_in[7];
  const float* nsq = (const float*)d_in[8];
  const float* nsk = (const float*)d_in[9];
  const float* nsv = (const float*)d_in[10];
  const float* Wo  = (const float*)d_in[11];
  float* out = (float*)d_out;

  char* ws = (char*)d_ws;
  unsigned short* Xbf  = (unsigned short*)(ws);                       // 16,777,216 (dead after Q proj)
  unsigned short* Wqb  = (unsigned short*)(ws + 16777216);            // 524,288 x4 (Wq/k/v dead after projs)
  unsigned short* Wkb  = Wqb + 262144;
  unsigned short* Wvb  = Wkb + 262144;
  unsigned short* Wob  = Wvb + 262144;                                // LIVE until out_gemm
  unsigned short* Qbuf = (unsigned short*)(ws + 18874368);            // 8,519,680
  unsigned short* Kbuf = (unsigned short*)(ws + 27394048);            // 16,908,288
  unsigned short* Vbuf = (unsigned short*)(ws + 44302336);            // 16,908,288 (dead after vtrans)
  unsigned short* Att  = (unsigned short*)(ws + 61210624);            // 8,519,680
  unsigned short* Vtg  = (unsigned short*)(ws + 69730304);            // 16,908,288 -> total 86,638,592
  // split-K partials overlay the dead Xbf+Wq/k/v region [0, 18,349,568):
  //   Po:  2 splits x 32 bh x 2080 q x 64 d x bf16 = 17,039,360 B at ws+0
  //   Pml: 2 x 32 x 2080 x float2               =  1,064,960 B at ws+17,039,360
  //   end = 18,104,320 < 18,349,568 (Wob untouched)
  unsigned short* Po  = (unsigned short*)(ws);
  float2*         Pml = (float2*)(ws + 17039360);
  if (ws_size < 86638592) return;   // insufficient scratch -> visible first-call failure

  cvt_f32_bf16_v4<<<dim3(8192), dim3(256), 0, stream>>>(seq, Xbf, 2097152);
  cvt_w4<<<dim3(256, 4), dim3(256), 0, stream>>>(Wq, Wk, Wv, Wo, Wqb);
  proj_gemm<<<dim3(128, 4), dim3(256), 0, stream>>>(Xbf, Wkb, Kbuf, 12, 0, KLEN, 1.f);
  proj_gemm<<<dim3(128, 4), dim3(256), 0, stream>>>(Xbf, Wvb, Vbuf, 12, 0, KLEN, 1.f);
  proj_gemm<<<dim3(64, 4), dim3(256), 0, stream>>>(Xbf, Wqb, Qbuf, 11, 2048, QLEN, QSCALE);
  ns_proj<<<dim3(4, 32, 3), dim3(256), 0, stream>>>(nst, nsq, nsk, nsv, Qbuf, Kbuf, Vbuf);
  vtrans<<<dim3(65, 32), dim3(256), 0, stream>>>(Vbuf, Vtg);
  attn_kernel<<<dim3(66, 8, 4), dim3(256), 0, stream>>>(Qbuf, Kbuf, Vtg, Po, Pml);
  attn_combine<<<dim3(65, 32), dim3(256), 0, stream>>>(Po, Pml, Att);
  out_gemm<<<dim3(65, 4), dim3(256), 0, stream>>>(Att, Wob, out);
}

// Round 11
// 227.148 us; speedup vs baseline: 1.5536x; 1.0273x over previous
//
#include <hip/hip_runtime.h>

// ---------------- problem constants ----------------
#define NBATCH 4
#define SEQ    4096
#define DMODEL 512
#define NHEAD  8
#define HDIM   64
#define NSN    32
#define NXT    2048
#define QLEN   2080   // NXT + NSN
#define KLEN   4128   // SEQ + NSN

using bf16x8 = __attribute__((ext_vector_type(8))) short;
using f32x4  = __attribute__((ext_vector_type(4))) float;

typedef __attribute__((address_space(1))) unsigned int gu32;
typedef __attribute__((address_space(3))) unsigned int lu32;

// Q projection pre-scale: SCALE * log2(e) — softmax runs in exp2 domain
#define QSCALE 0.18033688f

__device__ __forceinline__ unsigned short f2bf(float f) {
  unsigned int u = __float_as_uint(f);
  u += 0x7FFF + ((u >> 16) & 1);          // RTNE
  return (unsigned short)(u >> 16);
}

__device__ __forceinline__ float bf2f(unsigned short u) {
  return __uint_as_float((unsigned int)u << 16);
}

__device__ __forceinline__ f32x4 mfma16(bf16x8 a, bf16x8 b, f32x4 c) {
  return __builtin_amdgcn_mfma_f32_16x16x32_bf16(a, b, c, 0, 0, 0);
}

__device__ __forceinline__ void gload_lds16(const void* g, void* lds_base) {
  __builtin_amdgcn_global_load_lds((const gu32*)g, (lu32*)lds_base, 16, 0, 0);
}

__device__ __forceinline__ unsigned int cvt_pk_bf16(float lo, float hi) {
  unsigned int r;
  asm("v_cvt_pk_bf16_f32 %0, %1, %2" : "=v"(r) : "v"(lo), "v"(hi));
  return r;
}

// ---------------- fp32 -> bf16 converts ----------------
__global__ __launch_bounds__(256) void cvt_f32_bf16_v4(const float* __restrict__ src,
                                                       unsigned short* __restrict__ dst, int n4) {
  int i = blockIdx.x * 256 + threadIdx.x;
  if (i >= n4) return;
  float4 v = reinterpret_cast<const float4*>(src)[i];
  ushort4 r;
  r.x = f2bf(v.x); r.y = f2bf(v.y); r.z = f2bf(v.z); r.w = f2bf(v.w);
  reinterpret_cast<ushort4*>(dst)[i] = r;
}

__global__ __launch_bounds__(256) void cvt_w4(const float* __restrict__ a, const float* __restrict__ b,
                                              const float* __restrict__ c, const float* __restrict__ d,
                                              unsigned short* __restrict__ dst) {
  const float* s = blockIdx.y == 0 ? a : blockIdx.y == 1 ? b : blockIdx.y == 2 ? c : d;
  int i = blockIdx.x * 256 + threadIdx.x;   // 65536 float4 per matrix
  float4 v = reinterpret_cast<const float4*>(s)[i];
  ushort4 r;
  r.x = f2bf(v.x); r.y = f2bf(v.y); r.z = f2bf(v.z); r.w = f2bf(v.w);
  reinterpret_cast<ushort4*>(dst)[(size_t)blockIdx.y * 65536 + i] = r;
}

// ---------------- seq projection GEMM (m97 structure, known-good) ----------------
__global__ __launch_bounds__(256) void proj_gemm(const unsigned short* __restrict__ X,
                                                 const unsigned short* __restrict__ W,
                                                 unsigned short* __restrict__ Out,
                                                 int rpb_shift, int row_off, int out_L, float scale) {
  __shared__ unsigned short As[128 * 32];
  __shared__ unsigned short Bs[128 * 32];
  const int tid = threadIdx.x;
  const int w = tid >> 6, l = tid & 63;
  const int lg = l >> 4, lr = l & 15;
  const int row0 = blockIdx.x * 128, col0 = blockIdx.y * 128;
  const int wr = (w >> 1) * 64, wc = (w & 1) * 64;
  const int mask = (1 << rpb_shift) - 1;

  f32x4 acc[4][4];
#pragma unroll
  for (int m = 0; m < 4; ++m)
#pragma unroll
    for (int n = 0; n < 4; ++n) acc[m][n] = (f32x4){0.f, 0.f, 0.f, 0.f};

  const int sr = w * 16 + (l >> 2);
  const int sc = (l & 3) * 8;

  for (int k0 = 0; k0 < 512; k0 += 32) {
#pragma unroll
    for (int i = 0; i < 2; ++i) {
      int gr = row0 + sr + i * 64;
      int xrow = ((gr >> rpb_shift) << 12) + row_off + (gr & mask);
      const unsigned short* gpa = X + (size_t)xrow * 512 + k0 + sc;
      gload_lds16(gpa, (char*)As + i * 4096 + w * 1024);
      const unsigned short* gpb = W + (size_t)(col0 + sr + i * 64) * 512 + k0 + sc;
      gload_lds16(gpb, (char*)Bs + i * 4096 + w * 1024);
    }
    __syncthreads();
    bf16x8 av[4], bv[4];
#pragma unroll
    for (int m = 0; m < 4; ++m) av[m] = *(const bf16x8*)&As[(wr + m * 16 + lr) * 32 + lg * 8];
#pragma unroll
    for (int n = 0; n < 4; ++n) bv[n] = *(const bf16x8*)&Bs[(wc + n * 16 + lr) * 32 + lg * 8];
#pragma unroll
    for (int m = 0; m < 4; ++m)
#pragma unroll
      for (int n = 0; n < 4; ++n) acc[m][n] = mfma16(av[m], bv[n], acc[m][n]);
    __syncthreads();
  }

#pragma unroll
  for (int m = 0; m < 4; ++m) {
    int crow = row0 + wr + m * 16 + lg * 4;
#pragma unroll
    for (int n = 0; n < 4; ++n) {
      int ccol = col0 + wc + n * 16 + lr;
      int hh = ccol >> 6, dd = ccol & 63;
#pragma unroll
      for (int r = 0; r < 4; ++r) {
        int cr = crow + r;
        int bb = cr >> rpb_shift, ii = cr & mask;
        Out[(((size_t)bb * NHEAD + hh) * out_L + ii) * HDIM + dd] = f2bf(acc[m][n][r] * scale);
      }
    }
  }
}

// ---------------- ns projections ----------------
__global__ __launch_bounds__(256) void ns_proj(const float* __restrict__ nst,
                                               const float* __restrict__ Wnq, const float* __restrict__ Wnk,
                                               const float* __restrict__ Wnv,
                                               unsigned short* __restrict__ Qb, unsigned short* __restrict__ Kb,
                                               unsigned short* __restrict__ Vb) {
  const int oc = blockIdx.x, n = blockIdx.y, p = blockIdx.z;
  const float* W = p == 0 ? Wnq : p == 1 ? Wnk : Wnv;
  unsigned short* Out = p == 0 ? Qb : p == 1 ? Kb : Vb;
  const int out_L = p == 0 ? QLEN : KLEN;
  const int orow = p == 0 ? NXT + n : SEQ + n;
  const float scale = p == 0 ? QSCALE : 1.f;

  __shared__ float xs[NBATCH][DMODEL];
  __shared__ float red[NBATCH][128];
  const int tid = threadIdx.x;
  for (int idx = tid; idx < NBATCH * DMODEL; idx += 256)
    xs[idx >> 9][idx & 511] = nst[(size_t)((idx >> 9) * NSN + n) * DMODEL + (idx & 511)];
  __syncthreads();

  const int o = oc * 128 + (tid & 127);
  const int dh = tid >> 7;
  float a0 = 0.f, a1 = 0.f, a2 = 0.f, a3 = 0.f;
  const float* wp = W + (size_t)n * DMODEL * DMODEL + o;
#pragma unroll 8
  for (int d = dh * 256; d < dh * 256 + 256; ++d) {
    float wv = wp[(size_t)d * DMODEL];
    a0 += xs[0][d] * wv; a1 += xs[1][d] * wv; a2 += xs[2][d] * wv; a3 += xs[3][d] * wv;
  }
  if (dh == 1) { red[0][tid & 127] = a0; red[1][tid & 127] = a1; red[2][tid & 127] = a2; red[3][tid & 127] = a3; }
  __syncthreads();
  if (dh == 0) {
    a0 += red[0][tid & 127]; a1 += red[1][tid & 127]; a2 += red[2][tid & 127]; a3 += red[3][tid & 127];
    int hh = o >> 6, dd = o & 63;
    float v[4] = {a0, a1, a2, a3};
#pragma unroll
    for (int b = 0; b < NBATCH; ++b)
      Out[(((size_t)b * NHEAD + hh) * out_L + orow) * HDIM + dd] = f2bf(v[b] * scale);
  }
}

// ---------------- global V transpose: Vt[bh][d][kv] = V[bh][kv][d] ----------------
__global__ __launch_bounds__(256) void vtrans(const unsigned short* __restrict__ V,
                                              unsigned short* __restrict__ Vt) {
  __shared__ unsigned short t[64 * 64];
  const int tid = threadIdx.x;
  const int kv0 = blockIdx.x * 64, bh = blockIdx.y;
  const unsigned short* Vhp = V + (size_t)bh * KLEN * HDIM;
  unsigned short* Vtp = Vt + (size_t)bh * HDIM * KLEN;

#pragma unroll
  for (int i = 0; i < 2; ++i) {
    int c = i * 256 + tid;
    int row = c >> 3, c8 = c & 7;
    int kvg = kv0 + row; if (kvg > KLEN - 1) kvg = KLEN - 1;
    int4 v4 = *(const int4*)(Vhp + (size_t)kvg * HDIM + c8 * 8);
    *(int4*)&t[row * 64 + ((c8 ^ ((row >> 3) & 7)) * 8)] = v4;
  }
  __syncthreads();
#pragma unroll
  for (int i = 0; i < 2; ++i) {
    int c = i * 256 + tid;
    int d = c >> 3, k8 = c & 7;
    if (kv0 + k8 * 8 <= KLEN - 8) {
      unsigned int wd[4];
#pragma unroll
      for (int jj = 0; jj < 4; ++jj) {
        int ka = k8 * 8 + jj * 2, kb2 = ka + 1;
        unsigned int lo = t[ka  * 64 + (((d >> 3) ^ ((ka  >> 3) & 7)) * 8) + (d & 7)];
        unsigned int hi = t[kb2 * 64 + (((d >> 3) ^ ((kb2 >> 3) & 7)) * 8) + (d & 7)];
        wd[jj] = lo | (hi << 16);
      }
      int4 o; o.x = wd[0]; o.y = wd[1]; o.z = wd[2]; o.w = wd[3];
      *(int4*)(Vtp + (size_t)d * KLEN + kv0 + k8 * 8) = o;
    }
  }
}

// ---------------- flash attention (R11: split-K x3, single-buffer LDS) ----------------
// Grid (99, 8, 4): blockIdx.x = (qb, split of 3); disjoint kv thirds -> 3168 blocks
// (12.4/CU; R10's 2112 at 8.25/CU left occupancy at 32%, VALU 67% idle-limited).
// sp<2 partials in region A (dead Xbf/Wq-v), sp==2 in region B (dead Vbuf).
// In-tile machinery identical to R10 (swapped-operand, in-reg P redistribution).
__global__ __launch_bounds__(256) void attn_kernel(const unsigned short* __restrict__ Qb,
                                                   const unsigned short* __restrict__ Kb,
                                                   const unsigned short* __restrict__ Vtg,
                                                   unsigned short* __restrict__ PoA,
                                                   float2* __restrict__ PmlA,
                                                   unsigned short* __restrict__ PoB,
                                                   float2* __restrict__ PmlB) {
  __shared__ unsigned short Ks[64 * 64];   // 8 KB [kv][d] swizzled
  __shared__ unsigned short Vs[64 * 64];   // 8 KB [d][kv] swizzled

  const int tid = threadIdx.x;
  const int w = tid >> 6, l = tid & 63;
  const int lg = l >> 4, lr = l & 15;
  const bool geven = (l & 16) == 0;
  const int bx = (int)blockIdx.x;
  const int qb = 32 - bx / 3;                          // big q-blocks first
  const int sp = bx - 3 * (32 - qb);
  const int bh = (int)blockIdx.z * NHEAD + (int)blockIdx.y;
  const int q0 = qb * 64;
  const int base = NXT + q0;
  const int nkb = (base >> 6) + 1;                     // total tiles for this q-block
  const int t0 = (sp * nkb) / 3;
  const int t1 = ((sp + 1) * nkb) / 3;

  const unsigned short* Qh = Qb + (size_t)bh * QLEN * HDIM;
  const unsigned short* Kh = Kb + (size_t)bh * KLEN * HDIM;
  const unsigned short* Vh = Vtg + (size_t)bh * HDIM * KLEN;   // [64][KLEN]

  int qrow = q0 + w * 16 + lr; if (qrow > QLEN - 1) qrow = QLEN - 1;
  const bf16x8 qa0 = *(const bf16x8*)(Qh + (size_t)qrow * HDIM + lg * 8);
  const bf16x8 qa1 = *(const bf16x8*)(Qh + (size_t)qrow * HDIM + 32 + lg * 8);

  f32x4 acc[4];
#pragma unroll
  for (int n = 0; n < 4; ++n) acc[n] = (f32x4){0.f, 0.f, 0.f, 0.f};
  float m_r = 0.f, lsum = 0.f;                         // per-lane scalars (q = l&15)

  const bf16x8 ones = {(short)0x3F80, (short)0x3F80, (short)0x3F80, (short)0x3F80,
                       (short)0x3F80, (short)0x3F80, (short)0x3F80, (short)0x3F80};

  // staging lane geometry (involutive chunk swizzle, rule #21)
  const int rloc = l >> 3;
  const int jsrc = ((l & 7) ^ rloc) * 8;

  for (int kb = t0; kb < t1; ++kb) {
    const int kv0 = kb * 64;
    // stage this tile (single buffer): waves cooperatively DMA K and V
    if (kv0 + 64 <= KLEN) {
#pragma unroll
      for (int i = 0; i < 2; ++i) {
        const int r8 = (w * 2 + i) * 8;
        gload_lds16(Kh + (size_t)(kv0 + r8 + rloc) * HDIM + jsrc, &Ks[r8 * 64]);
        gload_lds16(Vh + (size_t)(r8 + rloc) * KLEN + kv0 + jsrc, &Vs[r8 * 64]);
      }
    } else {
#pragma unroll
      for (int i = 0; i < 2; ++i) {
        const int r8 = (w * 2 + i) * 8;
        int kr = kv0 + r8 + rloc; if (kr > KLEN - 1) kr = KLEN - 1;
        gload_lds16(Kh + (size_t)kr * HDIM + jsrc, &Ks[r8 * 64]);
        int vc = kv0 + jsrc; if (vc > KLEN - 8) vc = KLEN - 8;
        gload_lds16(Vh + (size_t)(r8 + rloc) * KLEN + vc, &Vs[r8 * 64]);
      }
    }
    __syncthreads();                                   // DMA drained, tile ready

    // S^T = K Q^T - m : lane owns q=l&15; s[n][r] is kv = kv0 + n*16 + lg*4 + r
    const f32x4 minit = {-m_r, -m_r, -m_r, -m_r};
    f32x4 s[4];
#pragma unroll
    for (int n = 0; n < 4; ++n) {
      const int rk = n * 16 + lr;
      const bf16x8 k0 = *(const bf16x8*)&Ks[rk * 64 + ((lg ^ (rk & 7)) * 8)];
      const bf16x8 k1 = *(const bf16x8*)&Ks[rk * 64 + (((4 + lg) ^ (rk & 7)) * 8)];
      s[n] = mfma16(k0, qa0, minit);                   // swapped operands
      s[n] = mfma16(k1, qa1, s[n]);
    }

    if (kb == nkb - 1) {                               // causal mask (diag tile, sp==2)
      const int qk_lim = base + w * 16 + lr;
#pragma unroll
      for (int n = 0; n < 4; ++n)
#pragma unroll
        for (int r = 0; r < 4; ++r)
          if (kv0 + n * 16 + lg * 4 + r > qk_lim) s[n][r] = -1e30f;
    }

    // local max via v_max3-friendly triples; __any makes the check wave-global
    float a3 = fmaxf(fmaxf(s[0][0], s[0][1]), s[0][2]);
    float b3 = fmaxf(fmaxf(s[0][3], s[1][0]), s[1][1]);
    float c3 = fmaxf(fmaxf(s[1][2], s[1][3]), s[2][0]);
    float d3 = fmaxf(fmaxf(s[2][1], s[2][2]), s[2][3]);
    float e3 = fmaxf(fmaxf(s[3][0], s[3][1]), s[3][2]);
    float rl = fmaxf(fmaxf(a3, b3), c3);
    rl = fmaxf(fmaxf(rl, d3), e3);
    rl = fmaxf(rl, s[3][3]);

    if (__any(rl > 11.5f)) {                           // T13 defer-max (rare branch)
      float rmax = fmaxf(rl, __shfl_xor(rl, 16));      // full cross-q-lane max
      rmax = fmaxf(rmax, __shfl_xor(rmax, 32));
      float dl = fmaxf(rmax, 0.f);
      float sc = exp2f(-dl);
      lsum *= sc; m_r += dl;
#pragma unroll
      for (int n = 0; n < 4; ++n) {
        acc[n][0] *= sc; acc[n][1] *= sc; acc[n][2] *= sc; acc[n][3] *= sc;
#pragma unroll
        for (int r = 0; r < 4; ++r) s[n][r] = exp2f(s[n][r] - dl);
      }
    } else {
#pragma unroll
      for (int n = 0; n < 4; ++n)
#pragma unroll
        for (int r = 0; r < 4; ++r) s[n][r] = exp2f(s[n][r]);
    }

    // ---- P redistribution to PV B-operand frags (registers only, as R9) ----
    unsigned int wpk[4][2];
#pragma unroll
    for (int n = 0; n < 4; ++n) {
      wpk[n][0] = cvt_pk_bf16(s[n][0], s[n][1]);
      wpk[n][1] = cvt_pk_bf16(s[n][2], s[n][3]);
    }
    bf16x8 pb[2];
#pragma unroll
    for (int ks = 0; ks < 2; ++ks) {
      unsigned int A0 = wpk[2 * ks][0], B0 = wpk[2 * ks + 1][0];
      unsigned int A1 = wpk[2 * ks][1], B1 = wpk[2 * ks + 1][1];
      asm("v_permlane32_swap_b32 %0, %1" : "+v"(A0), "+v"(B0));
      asm("v_permlane32_swap_b32 %0, %1" : "+v"(A1), "+v"(B1));
      unsigned int sA0 = __builtin_amdgcn_ds_swizzle(A0, 0x401F);  // lane ^16
      unsigned int sA1 = __builtin_amdgcn_ds_swizzle(A1, 0x401F);
      unsigned int sB0 = __builtin_amdgcn_ds_swizzle(B0, 0x401F);
      unsigned int sB1 = __builtin_amdgcn_ds_swizzle(B1, 0x401F);
      int4 words;
      words.x = geven ? A0 : sB0;
      words.y = geven ? A1 : sB1;
      words.z = geven ? sA0 : B0;
      words.w = geven ? sA1 : B1;
      pb[ks] = *(bf16x8*)&words;    // B-frag: P[kv=32ks+(l>>4)*8+j][q=l&15]
    }

    // lsum via ones-MFMA (A=ones)
    f32x4 acc_s = (f32x4){0.f, 0.f, 0.f, 0.f};
    acc_s = mfma16(ones, pb[0], acc_s);
    acc_s = mfma16(ones, pb[1], acc_s);
    lsum += acc_s[0];

    // PV: out^T[d][q] += V^T[d][kv] P[kv][q]
#pragma unroll
    for (int n = 0; n < 4; ++n) {
      const int rv = n * 16 + lr;
#pragma unroll
      for (int ks = 0; ks < 2; ++ks) {
        const bf16x8 vv = *(const bf16x8*)&Vs[rv * 64 + (((ks * 4 + lg) ^ (rv & 7)) * 8)];
        acc[n] = mfma16(vv, pb[ks], acc[n]);
      }
    }

    __syncthreads();   // readers done before next tile's DMA overwrites
  }

  // store partials (packed 8B): acc[n][r] -> [q][d = n*16+lg*4+r], unnormalized
  const int qi = q0 + w * 16 + lr;
  if (qi < QLEN) {
    unsigned short* po; float2* pml; size_t rowp;
    if (sp < 2) { rowp = (size_t)(sp * 32 + bh) * QLEN + qi; po = PoA + rowp * 64; pml = PmlA + rowp; }
    else        { rowp = (size_t)bh * QLEN + qi;             po = PoB + rowp * 64; pml = PmlB + rowp; }
#pragma unroll
    for (int n = 0; n < 4; ++n) {
      ushort4 pk;
      pk.x = f2bf(acc[n][0]); pk.y = f2bf(acc[n][1]);
      pk.z = f2bf(acc[n][2]); pk.w = f2bf(acc[n][3]);
      *(ushort4*)(po + n * 16 + lg * 4) = pk;
    }
    if (l < 16) *pml = (float2){m_r, lsum};
  }
}

// ---------------- split-K combine (3-way) ----------------
// grid (65, 32): bh = blockIdx.y; idx covers (qi, d-chunk of 8)
__global__ __launch_bounds__(256) void attn_combine(const unsigned short* __restrict__ PoA,
                                                    const float2* __restrict__ PmlA,
                                                    const unsigned short* __restrict__ PoB,
                                                    const float2* __restrict__ PmlB,
                                                    unsigned short* __restrict__ Att) {
  const int bh = blockIdx.y;
  const int idx = blockIdx.x * 256 + threadIdx.x;
  const int qi = idx >> 3, dc = (idx & 7) * 8;
  const size_t row = (size_t)bh * QLEN + qi;
  const float2 ml0 = PmlA[row];
  const float2 ml1 = PmlA[(size_t)32 * QLEN + row];
  const float2 ml2 = PmlB[row];
  const float mm = fmaxf(fmaxf(ml0.x, ml1.x), ml2.x);
  float s0 = exp2f(ml0.x - mm), s1 = exp2f(ml1.x - mm), s2 = exp2f(ml2.x - mm);
  const float inv = 1.f / (ml0.y * s0 + ml1.y * s1 + ml2.y * s2);
  s0 *= inv; s1 *= inv; s2 *= inv;
  const bf16x8 o0 = *(const bf16x8*)(PoA + row * 64 + dc);
  const bf16x8 o1 = *(const bf16x8*)(PoA + ((size_t)32 * QLEN + row) * 64 + dc);
  const bf16x8 o2 = *(const bf16x8*)(PoB + row * 64 + dc);
  unsigned short out[8];
#pragma unroll
  for (int j = 0; j < 8; ++j)
    out[j] = f2bf(bf2f((unsigned short)o0[j]) * s0 + bf2f((unsigned short)o1[j]) * s1 +
                  bf2f((unsigned short)o2[j]) * s2);
  const int b = bh >> 3, h = bh & 7;
  *(int4*)(Att + ((size_t)b * QLEN + qi) * DMODEL + h * HDIM + dc) = *(int4*)out;
}

// ---------------- output GEMM (unchanged) ----------------
__global__ __launch_bounds__(256) void out_gemm(const unsigned short* __restrict__ A,
                                                const unsigned short* __restrict__ W,
                                                float* __restrict__ Out) {
  __shared__ unsigned short As[128 * 32];
  __shared__ unsigned short Bs[128 * 32];
  const int tid = threadIdx.x;
  const int w = tid >> 6, l = tid & 63;
  const int lg = l >> 4, lr = l & 15;
  const int row0 = blockIdx.x * 128, col0 = blockIdx.y * 128;
  const int wr = (w >> 1) * 64, wc = (w & 1) * 64;

  f32x4 acc[4][4];
#pragma unroll
  for (int m = 0; m < 4; ++m)
#pragma unroll
    for (int n = 0; n < 4; ++n) acc[m][n] = (f32x4){0.f, 0.f, 0.f, 0.f};

  const int sr = w * 16 + (l >> 2);
  const int sc = (l & 3) * 8;

  for (int k0 = 0; k0 < 512; k0 += 32) {
#pragma unroll
    for (int i = 0; i < 2; ++i) {
      const unsigned short* gpa = A + (size_t)(row0 + sr + i * 64) * 512 + k0 + sc;
      gload_lds16(gpa, (char*)As + i * 4096 + w * 1024);
      const unsigned short* gpb = W + (size_t)(col0 + sr + i * 64) * 512 + k0 + sc;
      gload_lds16(gpb, (char*)Bs + i * 4096 + w * 1024);
    }
    __syncthreads();
    bf16x8 av[4], bv[4];
#pragma unroll
    for (int m = 0; m < 4; ++m) av[m] = *(const bf16x8*)&As[(wr + m * 16 + lr) * 32 + lg * 8];
#pragma unroll
    for (int n = 0; n < 4; ++n) bv[n] = *(const bf16x8*)&Bs[(wc + n * 16 + lr) * 32 + lg * 8];
#pragma unroll
    for (int m = 0; m < 4; ++m)
#pragma unroll
      for (int n = 0; n < 4; ++n) acc[m][n] = mfma16(av[m], bv[n], acc[m][n]);
    __syncthreads();
  }

#pragma unroll
  for (int m = 0; m < 4; ++m) {
    int crow = row0 + wr + m * 16 + lg * 4;
#pragma unroll
    for (int n = 0; n < 4; ++n) {
      int ccol = col0 + wc + n * 16 + lr;
#pragma unroll
      for (int r = 0; r < 4; ++r) {
        int cr = crow + r;
        int bb = cr / QLEN, ii = cr - bb * QLEN;
        size_t off = ii < NXT
                       ? ((size_t)bb * NXT + ii) * DMODEL + ccol
                       : (size_t)NBATCH * NXT * DMODEL + ((size_t)bb * NSN + (ii - NXT)) * DMODEL + ccol;
        Out[off] = acc[m][n][r];
      }
    }
  }
}

// ---------------- host launch ----------------
extern "C" void kernel_launch(void* const* d_in, const int* in_sizes, int n_in,
                              void* d_out, int out_size, void* d_ws, size_t ws_size,
                              hipStream_t stream) {
  const float* seq = (const float*)d_in[0];
  const float* nst = (const float*)d_in[2];
  const float* Wq  = (const float*)d_in[5];
  const float* Wk  = (const float*)d_in[6];
  const float* Wv  = (const float*)d_in[7];
  const float* nsq = (const float*)d_in[8];
  const float* nsk = (const float*)d_in[9];
  const float* nsv = (const float*)d_in[10];
  const float* Wo  = (const float*)d_in[11];
  float* out = (float*)d_out;

  char* ws = (char*)d_ws;
  unsigned short* Xbf  = (unsigned short*)(ws);                       // 16,777,216 (dead after Q proj)
  unsigned short* Wqb  = (unsigned short*)(ws + 16777216);            // 524,288 x4 (Wq/k/v dead after projs)
  unsigned short* Wkb  = Wqb + 262144;
  unsigned short* Wvb  = Wkb + 262144;
  unsigned short* Wob  = Wvb + 262144;                                // LIVE until out_gemm
  unsigned short* Qbuf = (unsigned short*)(ws + 18874368);            // 8,519,680
  unsigned short* Kbuf = (unsigned short*)(ws + 27394048);            // 16,908,288
  unsigned short* Vbuf = (unsigned short*)(ws + 44302336);            // 16,908,288 (dead after vtrans)
  unsigned short* Att  = (unsigned short*)(ws + 61210624);            // 8,519,680
  unsigned short* Vtg  = (unsigned short*)(ws + 69730304);            // 16,908,288 -> total 86,638,592
  // split-K partials:
  //  region A (dead Xbf+Wq/k/v, [0, 18,349,568)): PoA 17,039,360 + PmlA 1,064,960 = 18,104,320 ✓
  //  region B (dead Vbuf, [44,302,336, 61,210,624)): PoB 8,519,680 + PmlB 532,480 ✓
  unsigned short* PoA  = (unsigned short*)(ws);
  float2*         PmlA = (float2*)(ws + 17039360);
  unsigned short* PoB  = (unsigned short*)(ws + 44302336);
  float2*         PmlB = (float2*)(ws + 52822016);
  if (ws_size < 86638592) return;   // insufficient scratch -> visible first-call failure

  cvt_f32_bf16_v4<<<dim3(8192), dim3(256), 0, stream>>>(seq, Xbf, 2097152);
  cvt_w4<<<dim3(256, 4), dim3(256), 0, stream>>>(Wq, Wk, Wv, Wo, Wqb);
  proj_gemm<<<dim3(128, 4), dim3(256), 0, stream>>>(Xbf, Wkb, Kbuf, 12, 0, KLEN, 1.f);
  proj_gemm<<<dim3(128, 4), dim3(256), 0, stream>>>(Xbf, Wvb, Vbuf, 12, 0, KLEN, 1.f);
  proj_gemm<<<dim3(64, 4), dim3(256), 0, stream>>>(Xbf, Wqb, Qbuf, 11, 2048, QLEN, QSCALE);
  ns_proj<<<dim3(4, 32, 3), dim3(256), 0, stream>>>(nst, nsq, nsk, nsv, Qbuf, Kbuf, Vbuf);
  vtrans<<<dim3(65, 32), dim3(256), 0, stream>>>(Vbuf, Vtg);
  attn_kernel<<<dim3(99, 8, 4), dim3(256), 0, stream>>>(Qbuf, Kbuf, Vtg, PoA, PmlA, PoB, PmlB);
  attn_combine<<<dim3(65, 32), dim3(256), 0, stream>>>(PoA, PmlA, PoB, PmlB, Att);
  out_gemm<<<dim3(65, 4), dim3(256), 0, stream>>>(Att, Wob, out);
}